// Round 2
// baseline (666.456 us; speedup 1.0000x reference)
//
#include <hip/hip_runtime.h>
#include <cstdint>
#include <cstddef>

// Problem dims
constexpr int Bv = 4096;   // batch
constexpr int Dv = 1024;   // feature dim
constexpr int Cv = 1000;   // classes
constexpr int Tv = 32;     // trees
constexpr int NI = 63;     // internal nodes per tree
constexpr int NL = 64;     // leaves per tree
constexpr int TN = Tv * NI;   // 2016 total internal nodes
constexpr int TL = Tv * NL;   // 2048 total leaves

// Workspace layout (in floats)
constexpr size_t OFF_SCAL = 0;                         // [0]=temp, [1..32]=w[t]
constexpr size_t OFF_S    = 64;                        // sigmoid values: B x TN
constexpr size_t OFF_P    = OFF_S + (size_t)Bv * TN;   // leaf probs: TL x C
constexpr size_t OFF_MUW  = OFF_P + (size_t)TL * Cv;   // mu*w: B x TL

// ---------------------------------------------------------------------------
// Scalars: temp = clip(exp(logT), 0.1, 5.0); w = softmax(tree_weights)
// ---------------------------------------------------------------------------
__global__ void k_scalars(const float* __restrict__ tw, const float* __restrict__ lt,
                          float* __restrict__ scal) {
    if (threadIdx.x == 0) {
        float temp = fminf(fmaxf(expf(lt[0]), 0.1f), 5.0f);
        scal[0] = temp;
        float m = -3.4e38f;
        for (int t = 0; t < Tv; ++t) m = fmaxf(m, tw[t]);
        float s = 0.f;
        for (int t = 0; t < Tv; ++t) { float e = expf(tw[t] - m); scal[1 + t] = e; s += e; }
        float inv = 1.0f / s;
        for (int t = 0; t < Tv; ++t) scal[1 + t] *= inv;
    }
}

// ---------------------------------------------------------------------------
// GEMM1 (NT): S[b,j] = sigmoid((x[b,:] . W[j,:] + bias[j]) / temp)
// A = x [Bv x Dv] row-major, W [TN x Dv] row-major.
// 64x64 tile, BK=16, 256 threads, 4x4 per thread.
// ---------------------------------------------------------------------------
template<int BM, int BN, int BK>
__global__ __launch_bounds__(256)
void k_gemm1(const float* __restrict__ A, const float* __restrict__ W,
             const float* __restrict__ bias, const float* __restrict__ scal,
             float* __restrict__ S) {
    __shared__ float As[BM][BK + 1];
    __shared__ float Ws[BN][BK + 1];
    const int bm = blockIdx.y * BM;
    const int bn = blockIdx.x * BN;
    const int tid = threadIdx.x;
    const int tx = tid & 15;       // output col group
    const int ty = tid >> 4;       // output row group
    const int lr = tid >> 2;       // staging row 0..63
    const int lc = (tid & 3) << 2; // staging col 0,4,8,12

    float acc[4][4] = {};

    for (int k0 = 0; k0 < Dv; k0 += BK) {
        const float4 av = *reinterpret_cast<const float4*>(&A[(size_t)(bm + lr) * Dv + k0 + lc]);
        float4 wv = make_float4(0.f, 0.f, 0.f, 0.f);
        if (bn + lr < TN)
            wv = *reinterpret_cast<const float4*>(&W[(size_t)(bn + lr) * Dv + k0 + lc]);
        As[lr][lc + 0] = av.x; As[lr][lc + 1] = av.y; As[lr][lc + 2] = av.z; As[lr][lc + 3] = av.w;
        Ws[lr][lc + 0] = wv.x; Ws[lr][lc + 1] = wv.y; Ws[lr][lc + 2] = wv.z; Ws[lr][lc + 3] = wv.w;
        __syncthreads();
        #pragma unroll
        for (int k = 0; k < BK; ++k) {
            float a[4], b[4];
            #pragma unroll
            for (int r = 0; r < 4; ++r) a[r] = As[ty * 4 + r][k];
            #pragma unroll
            for (int c = 0; c < 4; ++c) b[c] = Ws[tx * 4 + c][k];
            #pragma unroll
            for (int r = 0; r < 4; ++r)
                #pragma unroll
                for (int c = 0; c < 4; ++c)
                    acc[r][c] = fmaf(a[r], b[c], acc[r][c]);
        }
        __syncthreads();
    }

    const float invT = 1.0f / scal[0];
    #pragma unroll
    for (int r = 0; r < 4; ++r) {
        #pragma unroll
        for (int c = 0; c < 4; ++c) {
            const int j = bn + tx * 4 + c;
            if (j < TN) {
                const float z = (acc[r][c] + bias[j]) * invT;
                const float s = 1.0f / (1.0f + expf(-z));
                S[(size_t)(bm + ty * 4 + r) * TN + j] = s;
            }
        }
    }
}

// ---------------------------------------------------------------------------
// mu kernel: per (b,t), build 64 leaf path-probs from 63 sigmoids, fold w[t].
// Fully unrolled in-place level doubling (static register indexing).
// ---------------------------------------------------------------------------
__global__ __launch_bounds__(256)
void k_mu(const float* __restrict__ S, const float* __restrict__ scal,
          float* __restrict__ MUW) {
    const int idx = blockIdx.x * 256 + threadIdx.x;
    if (idx >= Bv * Tv) return;
    const int b = idx >> 5;   // / 32
    const int t = idx & 31;

    const float* sp = S + (size_t)b * TN + t * NI;
    float s[NI];
    #pragma unroll
    for (int i = 0; i < NI; ++i) s[i] = sp[i];

    float mu[NL];
    mu[0] = scal[1 + t];   // fold tree weight in at the root
    #pragma unroll
    for (int d = 0; d < 6; ++d) {
        const int width = 1 << d;
        #pragma unroll
        for (int i = width - 1; i >= 0; --i) {
            const float sv = s[width - 1 + i];
            const float m  = mu[i];
            mu[2 * i + 1] = m * sv;
            mu[2 * i]     = m * (1.0f - sv);
        }
    }

    float* op = MUW + (size_t)b * TL + t * NL;
    #pragma unroll
    for (int l = 0; l < NL; ++l) op[l] = mu[l];
}

// ---------------------------------------------------------------------------
// Leaf softmax: one block per (t,l) row of length C.
// ---------------------------------------------------------------------------
__global__ __launch_bounds__(256)
void k_leafsm(const float* __restrict__ LL, const float* __restrict__ scal,
              float* __restrict__ P) {
    const int r = blockIdx.x;          // t*64 + l
    const int tid = threadIdx.x;
    const float invT = 1.0f / scal[0];
    const float* row = LL + (size_t)r * Cv;
    float* pr = P + (size_t)r * Cv;
    __shared__ float redm[4];
    __shared__ float reds[4];

    float m = -3.4e38f;
    for (int c = tid; c < Cv; c += 256) m = fmaxf(m, row[c] * invT);
    #pragma unroll
    for (int o = 32; o > 0; o >>= 1) m = fmaxf(m, __shfl_down(m, o));
    if ((tid & 63) == 0) redm[tid >> 6] = m;
    __syncthreads();
    m = fmaxf(fmaxf(redm[0], redm[1]), fmaxf(redm[2], redm[3]));

    float sum = 0.f;
    for (int c = tid; c < Cv; c += 256) {
        const float e = expf(row[c] * invT - m);
        pr[c] = e;
        sum += e;
    }
    #pragma unroll
    for (int o = 32; o > 0; o >>= 1) sum += __shfl_down(sum, o);
    if ((tid & 63) == 0) reds[tid >> 6] = sum;
    __syncthreads();
    sum = reds[0] + reds[1] + reds[2] + reds[3];
    const float rs = 1.0f / sum;
    for (int c = tid; c < Cv; c += 256) pr[c] *= rs;
}

// ---------------------------------------------------------------------------
// GEMM2 (NN): out[b,c] = muw[b,:] . P[:,c]
// A = muw [Bv x TL] row-major, P [TL x Cv] row-major.
// ---------------------------------------------------------------------------
template<int BM, int BN, int BK>
__global__ __launch_bounds__(256)
void k_gemm2(const float* __restrict__ A, const float* __restrict__ Bm,
             float* __restrict__ Cm) {
    __shared__ float As[BM][BK + 1];
    __shared__ float Bs[BK][BN];
    const int bm = blockIdx.y * BM;
    const int bn = blockIdx.x * BN;
    const int tid = threadIdx.x;
    const int tx = tid & 15;
    const int ty = tid >> 4;
    const int alr = tid >> 2;        // A staging row 0..63
    const int alc = (tid & 3) << 2;  // A staging col 0,4,8,12
    const int blr = tid >> 4;        // B staging row 0..15
    const int blc = (tid & 15) << 2; // B staging col 0..60

    float acc[4][4] = {};

    for (int k0 = 0; k0 < TL; k0 += BK) {
        const float4 av = *reinterpret_cast<const float4*>(&A[(size_t)(bm + alr) * TL + k0 + alc]);
        float4 bv;
        const int col = bn + blc;
        if (col + 4 <= Cv) {
            bv = *reinterpret_cast<const float4*>(&Bm[(size_t)(k0 + blr) * Cv + col]);
        } else {
            bv.x = (col + 0 < Cv) ? Bm[(size_t)(k0 + blr) * Cv + col + 0] : 0.f;
            bv.y = (col + 1 < Cv) ? Bm[(size_t)(k0 + blr) * Cv + col + 1] : 0.f;
            bv.z = (col + 2 < Cv) ? Bm[(size_t)(k0 + blr) * Cv + col + 2] : 0.f;
            bv.w = (col + 3 < Cv) ? Bm[(size_t)(k0 + blr) * Cv + col + 3] : 0.f;
        }
        As[alr][alc + 0] = av.x; As[alr][alc + 1] = av.y; As[alr][alc + 2] = av.z; As[alr][alc + 3] = av.w;
        Bs[blr][blc + 0] = bv.x; Bs[blr][blc + 1] = bv.y; Bs[blr][blc + 2] = bv.z; Bs[blr][blc + 3] = bv.w;
        __syncthreads();
        #pragma unroll
        for (int k = 0; k < BK; ++k) {
            float a[4], b[4];
            #pragma unroll
            for (int r = 0; r < 4; ++r) a[r] = As[ty * 4 + r][k];
            #pragma unroll
            for (int c = 0; c < 4; ++c) b[c] = Bs[k][tx * 4 + c];
            #pragma unroll
            for (int r = 0; r < 4; ++r)
                #pragma unroll
                for (int c = 0; c < 4; ++c)
                    acc[r][c] = fmaf(a[r], b[c], acc[r][c]);
        }
        __syncthreads();
    }

    #pragma unroll
    for (int r = 0; r < 4; ++r) {
        #pragma unroll
        for (int c = 0; c < 4; ++c) {
            const int cc = bn + tx * 4 + c;
            if (cc < Cv)
                Cm[(size_t)(bm + ty * 4 + r) * Cv + cc] = acc[r][c];
        }
    }
}

// ---------------------------------------------------------------------------
extern "C" void kernel_launch(void* const* d_in, const int* in_sizes, int n_in,
                              void* d_out, int out_size, void* d_ws, size_t ws_size,
                              hipStream_t stream) {
    const float* x  = (const float*)d_in[0];  // [B, D]
    const float* sw = (const float*)d_in[1];  // [T, NI, D]
    const float* sb = (const float*)d_in[2];  // [T, NI]
    const float* ll = (const float*)d_in[3];  // [T, NL, C]
    const float* tw = (const float*)d_in[4];  // [T]
    const float* lt = (const float*)d_in[5];  // scalar

    float* out  = (float*)d_out;              // [B, C]
    float* ws   = (float*)d_ws;
    float* scal = ws + OFF_SCAL;
    float* S    = ws + OFF_S;
    float* P    = ws + OFF_P;
    float* MUW  = ws + OFF_MUW;

    k_scalars<<<1, 64, 0, stream>>>(tw, lt, scal);
    k_gemm1<64, 64, 16><<<dim3((TN + 63) / 64, Bv / 64), 256, 0, stream>>>(x, sw, sb, scal, S);
    k_leafsm<<<TL, 256, 0, stream>>>(ll, scal, P);
    k_mu<<<(Bv * Tv) / 256, 256, 0, stream>>>(S, scal, MUW);
    k_gemm2<64, 64, 16><<<dim3((Cv + 63) / 64, Bv / 64), 256, 0, stream>>>(MUW, P, out);
}

// Round 3
// 229.537 us; speedup vs baseline: 2.9035x; 2.9035x over previous
//
#include <hip/hip_runtime.h>
#include <cstdint>
#include <cstddef>

// Problem dims
constexpr int Bv = 4096;   // batch
constexpr int Dv = 1024;   // feature dim
constexpr int Cv = 1000;   // classes
constexpr int Tv = 32;     // trees
constexpr int NI = 63;     // internal nodes per tree
constexpr int NL = 64;     // leaves per tree
constexpr int TN = Tv * NI;   // 2016
constexpr int TL = Tv * NL;   // 2048
constexpr int Npad = 1024;    // padded class dim for gemm2 tiling

typedef _Float16 h8  __attribute__((ext_vector_type(8)));
typedef _Float16 h4  __attribute__((ext_vector_type(4)));
typedef short    s8v __attribute__((ext_vector_type(8)));
typedef unsigned short us8 __attribute__((ext_vector_type(8)));
typedef float    f4v __attribute__((ext_vector_type(4)));

// Workspace layout (float units). Total identical to round-2 baseline (74.8 MB).
constexpr size_t OFF_SCAL = 0;                                   // [0]=temp, [1..32]=w[t]
constexpr size_t OFF_S    = 64;                                  // fp32 S [Bv][TN]
constexpr size_t OFF_P    = OFF_S + (size_t)Bv * TN;             // fp32 P [TL][Cv]
constexpr size_t OFF_MUWH = OFF_P + (size_t)TL * Cv;             // ushort [Bv][TL]
constexpr size_t OFF_MUWL = OFF_MUWH + (size_t)Bv * TL / 2;      // ushort [Bv][TL]
// P^T (bf16 hi/lo, [Npad][TL]) aliases the S region: S is dead after k_mu,
// and k_tp is launched after k_mu on the same stream.
constexpr size_t OFF_PTH  = OFF_S;
constexpr size_t OFF_PTL  = OFF_S + (size_t)Npad * TL / 2;

// bf16 round-to-nearest-even from fp32 (bit trick, valid for all finite inputs)
__device__ __forceinline__ unsigned short f2bf_rn(float x) {
    unsigned u = __float_as_uint(x);
    return (unsigned short)((u + 0x7fffu + ((u >> 16) & 1u)) >> 16);
}
__device__ __forceinline__ float bf2f(unsigned short h) {
    return __uint_as_float(((unsigned)h) << 16);
}

// ---------------------------------------------------------------------------
// Scalars: temp = clip(exp(logT), 0.1, 5.0); w = softmax(tree_weights)
// ---------------------------------------------------------------------------
__global__ void k_scalars(const float* __restrict__ tw, const float* __restrict__ lt,
                          float* __restrict__ scal) {
    if (threadIdx.x == 0) {
        float temp = fminf(fmaxf(expf(lt[0]), 0.1f), 5.0f);
        scal[0] = temp;
        float m = -3.4e38f;
        for (int t = 0; t < Tv; ++t) m = fmaxf(m, tw[t]);
        float s = 0.f;
        for (int t = 0; t < Tv; ++t) { float e = expf(tw[t] - m); scal[1 + t] = e; s += e; }
        float inv = 1.0f / s;
        for (int t = 0; t < Tv; ++t) scal[1 + t] *= inv;
    }
}

// ---------------------------------------------------------------------------
// GEMM1 via f16-split MFMA: S = sigmoid((x @ W^T + bias)/temp)
// x [Bv x Dv] rm, W [TN x Dv] rm (NT GEMM). 128x128 tile, BK=32, 4 waves
// each owning a 64x64 sub-tile (4x4 fragments of 16x16x32).
// hi/lo f16 split: acc += Ah*Bh + Ah*Bl + Al*Bh  (fp32 accumulate).
// ---------------------------------------------------------------------------
__global__ __launch_bounds__(256, 2)
void k_gemm1(const float* __restrict__ A, const float* __restrict__ W,
             const float* __restrict__ bias, const float* __restrict__ scal,
             float* __restrict__ S) {
    __shared__ _Float16 Ah[128][40];
    __shared__ _Float16 Al[128][40];
    __shared__ _Float16 Bh[128][40];
    __shared__ _Float16 Bl[128][40];

    const int tid  = threadIdx.x;
    const int bm   = blockIdx.y * 128;
    const int bn   = blockIdx.x * 128;
    const int lane = tid & 63;
    const int wv   = tid >> 6;
    const int wr   = wv >> 1;        // wave row (0..1)
    const int wc   = wv & 1;         // wave col (0..1)
    const int lrow = lane & 15;      // fragment row/col within 16
    const int kg   = (lane >> 4) * 8;// k-group offset (0,8,16,24)

    f4v acc[4][4] = {};

    for (int k0 = 0; k0 < Dv; k0 += 32) {
        // ---- stage A-slab and W-slab (fp32 -> f16 hi/lo) ----
        #pragma unroll
        for (int i = 0; i < 4; ++i) {
            const int idx = tid + i * 256;        // 0..1023
            const int row = idx >> 3;             // 0..127
            const int kc  = (idx & 7) << 2;       // 0,4,...,28
            const float4 av = *reinterpret_cast<const float4*>(&A[(size_t)(bm + row) * Dv + k0 + kc]);
            h4 ah, al;
            { _Float16 h;
              h = (_Float16)av.x; ah[0] = h; al[0] = (_Float16)(av.x - (float)h);
              h = (_Float16)av.y; ah[1] = h; al[1] = (_Float16)(av.y - (float)h);
              h = (_Float16)av.z; ah[2] = h; al[2] = (_Float16)(av.z - (float)h);
              h = (_Float16)av.w; ah[3] = h; al[3] = (_Float16)(av.w - (float)h); }
            *reinterpret_cast<h4*>(&Ah[row][kc]) = ah;
            *reinterpret_cast<h4*>(&Al[row][kc]) = al;

            const int j = bn + row;
            float4 wv4 = make_float4(0.f, 0.f, 0.f, 0.f);
            if (j < TN)
                wv4 = *reinterpret_cast<const float4*>(&W[(size_t)j * Dv + k0 + kc]);
            h4 bh, bl;
            { _Float16 h;
              h = (_Float16)wv4.x; bh[0] = h; bl[0] = (_Float16)(wv4.x - (float)h);
              h = (_Float16)wv4.y; bh[1] = h; bl[1] = (_Float16)(wv4.y - (float)h);
              h = (_Float16)wv4.z; bh[2] = h; bl[2] = (_Float16)(wv4.z - (float)h);
              h = (_Float16)wv4.w; bh[3] = h; bl[3] = (_Float16)(wv4.w - (float)h); }
            *reinterpret_cast<h4*>(&Bh[row][kc]) = bh;
            *reinterpret_cast<h4*>(&Bl[row][kc]) = bl;
        }
        __syncthreads();

        // ---- fragment reads ----
        h8 a_h[4], a_l[4], b_h[4], b_l[4];
        #pragma unroll
        for (int mf = 0; mf < 4; ++mf) {
            const int r = wr * 64 + mf * 16 + lrow;
            a_h[mf] = *reinterpret_cast<const h8*>(&Ah[r][kg]);
            a_l[mf] = *reinterpret_cast<const h8*>(&Al[r][kg]);
        }
        #pragma unroll
        for (int nf = 0; nf < 4; ++nf) {
            const int c = wc * 64 + nf * 16 + lrow;
            b_h[nf] = *reinterpret_cast<const h8*>(&Bh[c][kg]);
            b_l[nf] = *reinterpret_cast<const h8*>(&Bl[c][kg]);
        }

        // ---- 3-pass split MFMA (independent acc chains interleaved) ----
        #pragma unroll
        for (int mf = 0; mf < 4; ++mf)
            #pragma unroll
            for (int nf = 0; nf < 4; ++nf)
                acc[mf][nf] = __builtin_amdgcn_mfma_f32_16x16x32_f16(a_h[mf], b_h[nf], acc[mf][nf], 0, 0, 0);
        #pragma unroll
        for (int mf = 0; mf < 4; ++mf)
            #pragma unroll
            for (int nf = 0; nf < 4; ++nf)
                acc[mf][nf] = __builtin_amdgcn_mfma_f32_16x16x32_f16(a_h[mf], b_l[nf], acc[mf][nf], 0, 0, 0);
        #pragma unroll
        for (int mf = 0; mf < 4; ++mf)
            #pragma unroll
            for (int nf = 0; nf < 4; ++nf)
                acc[mf][nf] = __builtin_amdgcn_mfma_f32_16x16x32_f16(a_l[mf], b_h[nf], acc[mf][nf], 0, 0, 0);
        __syncthreads();
    }

    // ---- epilogue: bias, /temp, sigmoid ----
    const float invT = 1.0f / scal[0];
    #pragma unroll
    for (int nf = 0; nf < 4; ++nf) {
        const int col = bn + wc * 64 + nf * 16 + lrow;
        if (col >= TN) continue;
        const float bv = bias[col];
        #pragma unroll
        for (int mf = 0; mf < 4; ++mf) {
            #pragma unroll
            for (int r = 0; r < 4; ++r) {
                const int row = bm + wr * 64 + mf * 16 + (lane >> 4) * 4 + r;
                const float z = (acc[mf][nf][r] + bv) * invT;
                S[(size_t)row * TN + col] = 1.0f / (1.0f + __expf(-z));
            }
        }
    }
}

// ---------------------------------------------------------------------------
// mu kernel: per (b,t), 64 leaf path-probs from 63 sigmoids, fold w[t],
// write PRE-SPLIT bf16 hi/lo (for GEMM2's A operand).
// ---------------------------------------------------------------------------
__global__ __launch_bounds__(256)
void k_mu(const float* __restrict__ S, const float* __restrict__ scal,
          unsigned short* __restrict__ MH, unsigned short* __restrict__ ML) {
    const int idx = blockIdx.x * 256 + threadIdx.x;
    if (idx >= Bv * Tv) return;
    const int b = idx >> 5;
    const int t = idx & 31;

    const float* sp = S + (size_t)b * TN + t * NI;
    float s[NI];
    #pragma unroll
    for (int i = 0; i < NI; ++i) s[i] = sp[i];

    float mu[NL];
    mu[0] = scal[1 + t];
    #pragma unroll
    for (int d = 0; d < 6; ++d) {
        const int width = 1 << d;
        #pragma unroll
        for (int i = width - 1; i >= 0; --i) {
            const float sv = s[width - 1 + i];
            const float m  = mu[i];
            mu[2 * i + 1] = m * sv;
            mu[2 * i]     = m * (1.0f - sv);
        }
    }

    const size_t base = (size_t)b * TL + t * NL;
    #pragma unroll
    for (int c = 0; c < 8; ++c) {
        us8 vh, vl;
        #pragma unroll
        for (int j = 0; j < 8; ++j) {
            const float x = mu[c * 8 + j];
            const unsigned short hi = f2bf_rn(x);
            vh[j] = hi;
            vl[j] = f2bf_rn(x - bf2f(hi));
        }
        *reinterpret_cast<us8*>(&MH[base + c * 8]) = vh;
        *reinterpret_cast<us8*>(&ML[base + c * 8]) = vl;
    }
}

// ---------------------------------------------------------------------------
// Leaf softmax: one block per (t,l) row of length C. (writes fp32 P)
// ---------------------------------------------------------------------------
__global__ __launch_bounds__(256)
void k_leafsm(const float* __restrict__ LL, const float* __restrict__ scal,
              float* __restrict__ P) {
    const int r = blockIdx.x;
    const int tid = threadIdx.x;
    const float invT = 1.0f / scal[0];
    const float* row = LL + (size_t)r * Cv;
    float* pr = P + (size_t)r * Cv;
    __shared__ float redm[4];
    __shared__ float reds[4];

    float m = -3.4e38f;
    for (int c = tid; c < Cv; c += 256) m = fmaxf(m, row[c] * invT);
    #pragma unroll
    for (int o = 32; o > 0; o >>= 1) m = fmaxf(m, __shfl_down(m, o));
    if ((tid & 63) == 0) redm[tid >> 6] = m;
    __syncthreads();
    m = fmaxf(fmaxf(redm[0], redm[1]), fmaxf(redm[2], redm[3]));

    float sum = 0.f;
    for (int c = tid; c < Cv; c += 256) {
        const float e = expf(row[c] * invT - m);
        pr[c] = e;
        sum += e;
    }
    #pragma unroll
    for (int o = 32; o > 0; o >>= 1) sum += __shfl_down(sum, o);
    if ((tid & 63) == 0) reds[tid >> 6] = sum;
    __syncthreads();
    sum = reds[0] + reds[1] + reds[2] + reds[3];
    const float rs = 1.0f / sum;
    for (int c = tid; c < Cv; c += 256) pr[c] *= rs;
}

// ---------------------------------------------------------------------------
// Transpose + bf16-split P: fp32 P [TL][Cv] -> PTH/PTL bf16 [Npad][TL].
// Rows c in [Cv, Npad) are written as zeros (so GEMM2 needs no K-guards).
// ---------------------------------------------------------------------------
__global__ __launch_bounds__(256)
void k_tp(const float* __restrict__ P, unsigned short* __restrict__ PTH,
          unsigned short* __restrict__ PTL) {
    __shared__ float T[64][65];
    const int k0 = blockIdx.x * 64;   // leaf (K) tile
    const int c0 = blockIdx.y * 64;   // class (row of PT) tile
    const int tid = threadIdx.x;
    #pragma unroll
    for (int i = 0; i < 16; ++i) {
        const int idx = tid + i * 256;
        const int kk = idx >> 6, cc = idx & 63;
        const int c = c0 + cc;
        T[kk][cc] = (c < Cv) ? P[(size_t)(k0 + kk) * Cv + c] : 0.f;
    }
    __syncthreads();
    #pragma unroll
    for (int i = 0; i < 16; ++i) {
        const int idx = tid + i * 256;
        const int cc = idx >> 6, kk = idx & 63;
        const float x = T[kk][cc];
        const unsigned short hi = f2bf_rn(x);
        const unsigned short lo = f2bf_rn(x - bf2f(hi));
        PTH[(size_t)(c0 + cc) * TL + k0 + kk] = hi;
        PTL[(size_t)(c0 + cc) * TL + k0 + kk] = lo;
    }
}

// ---------------------------------------------------------------------------
// GEMM2 via bf16-split MFMA: out = muw @ P   (A pre-split [Bv][TL],
// B pre-split+transposed [Npad][TL]). 128x64 tile, BK=32, 4 waves 2x2,
// each wave 64x32 (4x2 fragments).
// ---------------------------------------------------------------------------
__global__ __launch_bounds__(256, 2)
void k_gemm2(const unsigned short* __restrict__ MH, const unsigned short* __restrict__ ML,
             const unsigned short* __restrict__ PTH, const unsigned short* __restrict__ PTL,
             float* __restrict__ out) {
    __shared__ unsigned short Ah[128][40];
    __shared__ unsigned short Al[128][40];
    __shared__ unsigned short Bh[64][40];
    __shared__ unsigned short Bl[64][40];

    const int tid  = threadIdx.x;
    const int bm   = blockIdx.y * 128;
    const int bn   = blockIdx.x * 64;
    const int lane = tid & 63;
    const int wv   = tid >> 6;
    const int wr   = wv >> 1;
    const int wc   = wv & 1;
    const int lrow = lane & 15;
    const int kg   = (lane >> 4) * 8;

    f4v acc[4][2] = {};

    for (int k0 = 0; k0 < TL; k0 += 32) {
        #pragma unroll
        for (int i = 0; i < 2; ++i) {
            const int idx = tid + i * 256;     // 0..511
            const int row = idx >> 2;          // 0..127
            const int kc  = (idx & 3) * 8;     // 0,8,16,24
            *reinterpret_cast<us8*>(&Ah[row][kc]) =
                *reinterpret_cast<const us8*>(&MH[(size_t)(bm + row) * TL + k0 + kc]);
            *reinterpret_cast<us8*>(&Al[row][kc]) =
                *reinterpret_cast<const us8*>(&ML[(size_t)(bm + row) * TL + k0 + kc]);
        }
        {
            const int row = tid >> 2;          // 0..63
            const int kc  = (tid & 3) * 8;
            *reinterpret_cast<us8*>(&Bh[row][kc]) =
                *reinterpret_cast<const us8*>(&PTH[(size_t)(bn + row) * TL + k0 + kc]);
            *reinterpret_cast<us8*>(&Bl[row][kc]) =
                *reinterpret_cast<const us8*>(&PTL[(size_t)(bn + row) * TL + k0 + kc]);
        }
        __syncthreads();

        s8v a_h[4], a_l[4], b_h[2], b_l[2];
        #pragma unroll
        for (int mf = 0; mf < 4; ++mf) {
            const int r = wr * 64 + mf * 16 + lrow;
            a_h[mf] = *reinterpret_cast<const s8v*>(&Ah[r][kg]);
            a_l[mf] = *reinterpret_cast<const s8v*>(&Al[r][kg]);
        }
        #pragma unroll
        for (int nf = 0; nf < 2; ++nf) {
            const int c = wc * 32 + nf * 16 + lrow;
            b_h[nf] = *reinterpret_cast<const s8v*>(&Bh[c][kg]);
            b_l[nf] = *reinterpret_cast<const s8v*>(&Bl[c][kg]);
        }

        #pragma unroll
        for (int mf = 0; mf < 4; ++mf)
            #pragma unroll
            for (int nf = 0; nf < 2; ++nf)
                acc[mf][nf] = __builtin_amdgcn_mfma_f32_16x16x32_bf16(a_h[mf], b_h[nf], acc[mf][nf], 0, 0, 0);
        #pragma unroll
        for (int mf = 0; mf < 4; ++mf)
            #pragma unroll
            for (int nf = 0; nf < 2; ++nf)
                acc[mf][nf] = __builtin_amdgcn_mfma_f32_16x16x32_bf16(a_h[mf], b_l[nf], acc[mf][nf], 0, 0, 0);
        #pragma unroll
        for (int mf = 0; mf < 4; ++mf)
            #pragma unroll
            for (int nf = 0; nf < 2; ++nf)
                acc[mf][nf] = __builtin_amdgcn_mfma_f32_16x16x32_bf16(a_l[mf], b_h[nf], acc[mf][nf], 0, 0, 0);
        __syncthreads();
    }

    #pragma unroll
    for (int nf = 0; nf < 2; ++nf) {
        const int col = bn + wc * 32 + nf * 16 + lrow;
        if (col >= Cv) continue;
        #pragma unroll
        for (int mf = 0; mf < 4; ++mf) {
            #pragma unroll
            for (int r = 0; r < 4; ++r) {
                const int row = bm + wr * 64 + mf * 16 + (lane >> 4) * 4 + r;
                out[(size_t)row * Cv + col] = acc[mf][nf][r];
            }
        }
    }
}

// ---------------------------------------------------------------------------
extern "C" void kernel_launch(void* const* d_in, const int* in_sizes, int n_in,
                              void* d_out, int out_size, void* d_ws, size_t ws_size,
                              hipStream_t stream) {
    const float* x  = (const float*)d_in[0];  // [B, D]
    const float* sw = (const float*)d_in[1];  // [T, NI, D]
    const float* sb = (const float*)d_in[2];  // [T, NI]
    const float* ll = (const float*)d_in[3];  // [T, NL, C]
    const float* tw = (const float*)d_in[4];  // [T]
    const float* lt = (const float*)d_in[5];  // scalar

    float* out  = (float*)d_out;              // [B, C]
    float* ws   = (float*)d_ws;
    float* scal = ws + OFF_SCAL;
    float* Sbuf = ws + OFF_S;
    float* Pbuf = ws + OFF_P;
    unsigned short* MH  = (unsigned short*)(ws + OFF_MUWH);
    unsigned short* ML  = (unsigned short*)(ws + OFF_MUWL);
    unsigned short* PTH = (unsigned short*)(ws + OFF_PTH);
    unsigned short* PTL = (unsigned short*)(ws + OFF_PTL);

    k_scalars<<<1, 64, 0, stream>>>(tw, lt, scal);
    k_gemm1<<<dim3(16, 32), 256, 0, stream>>>(x, sw, sb, scal, Sbuf);
    // k_mu must finish reading S before k_tp overwrites the S region (stream order).
    k_mu<<<(Bv * Tv) / 256, 256, 0, stream>>>(Sbuf, scal, MH, ML);
    k_leafsm<<<TL, 256, 0, stream>>>(ll, scal, Pbuf);
    k_tp<<<dim3(TL / 64, Npad / 64), 256, 0, stream>>>(Pbuf, PTH, PTL);
    k_gemm2<<<dim3(Npad / 64, Bv / 128), 256, 0, stream>>>(MH, ML, PTH, PTL, out);
}

// Round 4
// 146.521 us; speedup vs baseline: 4.5485x; 1.5666x over previous
//
#include <hip/hip_runtime.h>
#include <cstdint>
#include <cstddef>

// Problem dims
constexpr int Bv = 4096;   // batch
constexpr int Dv = 1024;   // feature dim
constexpr int Cv = 1000;   // classes
constexpr int Tv = 32;     // trees
constexpr int NI = 63;     // internal nodes per tree
constexpr int NL = 64;     // leaves per tree
constexpr int TN = Tv * NI;   // 2016
constexpr int TNp = 2048;     // padded internal-node dim (W rows zero-padded)
constexpr int TL = Tv * NL;   // 2048
constexpr int Npad = 1024;    // padded class dim for gemm2 tiling

typedef _Float16 h8  __attribute__((ext_vector_type(8)));
typedef _Float16 h4  __attribute__((ext_vector_type(4)));
typedef short    s8v __attribute__((ext_vector_type(8)));
typedef unsigned short us8 __attribute__((ext_vector_type(8)));
typedef float    f4v __attribute__((ext_vector_type(4)));

// ---------------------------------------------------------------------------
// Workspace layout (float units), with aliasing:
//   [OFF_XW ..)  Xh,Xl,Wh,Wl f16 splits (6M floats). MH (bf16, 4M floats)
//                ALIASES this region — k_mu runs after gemm1 (last X/W reader).
//   [OFF_S ..)   S fp32 [Bv][TN] (8.26M floats). PTH (bf16, 1M floats)
//                ALIASES this region — k_tp runs after k_mu (last S reader).
//   [OFF_P ..)   P fp32 [TL][Cv].
// Total ~16.6M floats = 66.4 MB (round-3 used 74.9 MB successfully).
// ---------------------------------------------------------------------------
constexpr size_t OFF_SCAL = 0;                                  // [0]=temp,[1..32]=w[t]
constexpr size_t OFF_XW   = 64;
constexpr size_t N_X      = (size_t)Bv * Dv;                    // 4,194,304
constexpr size_t N_W      = (size_t)TNp * Dv;                   // 2,097,152 (padded)
constexpr size_t XW_FLOATS = (2 * N_X + 2 * N_W) / 2;           // 6M floats
constexpr size_t OFF_S    = OFF_XW + XW_FLOATS;
constexpr size_t OFF_P    = OFF_S + (size_t)Bv * TN;
constexpr size_t OFF_MH   = OFF_XW;                             // alias
constexpr size_t OFF_PTH  = OFF_S;                              // alias

// bf16 round-to-nearest-even from fp32
__device__ __forceinline__ unsigned short f2bf_rn(float x) {
    unsigned u = __float_as_uint(x);
    return (unsigned short)((u + 0x7fffu + ((u >> 16) & 1u)) >> 16);
}

// async global->LDS, 16B per lane, dest = uniform base + lane*16
__device__ __forceinline__ void gll16(const void* gptr, void* lptr) {
    __builtin_amdgcn_global_load_lds(
        (const __attribute__((address_space(1))) unsigned int*)gptr,
        (__attribute__((address_space(3))) unsigned int*)lptr,
        16, 0, 0);
}

// ---------------------------------------------------------------------------
// Scalars: temp = clip(exp(logT), 0.1, 5.0); w = softmax(tree_weights)
// ---------------------------------------------------------------------------
__global__ void k_scalars(const float* __restrict__ tw, const float* __restrict__ lt,
                          float* __restrict__ scal) {
    if (threadIdx.x == 0) {
        float temp = fminf(fmaxf(expf(lt[0]), 0.1f), 5.0f);
        scal[0] = temp;
        float m = -3.4e38f;
        for (int t = 0; t < Tv; ++t) m = fmaxf(m, tw[t]);
        float s = 0.f;
        for (int t = 0; t < Tv; ++t) { float e = expf(tw[t] - m); scal[1 + t] = e; s += e; }
        float inv = 1.0f / s;
        for (int t = 0; t < Tv; ++t) scal[1 + t] *= inv;
    }
}

// ---------------------------------------------------------------------------
// Split fp32 -> f16 hi/lo. idx >= n_src (zero-pad region) writes zeros.
// ---------------------------------------------------------------------------
__global__ __launch_bounds__(256)
void k_split(const float* __restrict__ src, _Float16* __restrict__ hi,
             _Float16* __restrict__ lo, int n_src, int n_tot) {
    const int i4 = (blockIdx.x * 256 + threadIdx.x) * 4;
    if (i4 >= n_tot) return;
    float4 v = make_float4(0.f, 0.f, 0.f, 0.f);
    if (i4 < n_src) v = *reinterpret_cast<const float4*>(&src[i4]);
    h4 vh, vl;
    _Float16 h;
    h = (_Float16)v.x; vh[0] = h; vl[0] = (_Float16)(v.x - (float)h);
    h = (_Float16)v.y; vh[1] = h; vl[1] = (_Float16)(v.y - (float)h);
    h = (_Float16)v.z; vh[2] = h; vl[2] = (_Float16)(v.z - (float)h);
    h = (_Float16)v.w; vh[3] = h; vl[3] = (_Float16)(v.w - (float)h);
    *reinterpret_cast<h4*>(&hi[i4]) = vh;
    *reinterpret_cast<h4*>(&lo[i4]) = vl;
}

// ---------------------------------------------------------------------------
// GEMM1 (NT, f16 3-pass split MFMA): S = sigmoid((x @ W^T + bias)/temp)
// Pre-split inputs: Xh/Xl [Bv][Dv], Wh/Wl [TNp][Dv] f16.
// 128x128 tile, BK=32, 4 waves (2x2), wave = 64x64 (4x4 frags of 16x16x32).
// Staging via global_load_lds into linear [128][32] f16 LDS.
// ---------------------------------------------------------------------------
__global__ __launch_bounds__(256, 2)
void k_gemm1(const _Float16* __restrict__ Xh, const _Float16* __restrict__ Xl,
             const _Float16* __restrict__ Wh, const _Float16* __restrict__ Wl,
             const float* __restrict__ bias, const float* __restrict__ scal,
             float* __restrict__ S) {
    __shared__ _Float16 Ah[128][32];
    __shared__ _Float16 Al[128][32];
    __shared__ _Float16 Bh[128][32];
    __shared__ _Float16 Bl[128][32];

    const int tid  = threadIdx.x;
    const int bm   = blockIdx.y * 128;
    const int bn   = blockIdx.x * 128;
    const int lane = tid & 63;
    const int wv   = tid >> 6;
    const int wr   = wv >> 1;
    const int wc   = wv & 1;
    const int lrow = lane & 15;
    const int kg   = (lane >> 4) * 8;
    const int slr  = lane >> 2;        // staging row within 16-row chunk
    const int slc  = (lane & 3) * 8;   // staging f16 col

    f4v acc[4][4] = {};

    for (int k0 = 0; k0 < Dv; k0 += 32) {
        // ---- stage 4 slabs via global_load_lds (2 chunks/wave/slab) ----
        #pragma unroll
        for (int i = 0; i < 2; ++i) {
            const int ch  = wv * 2 + i;            // chunk 0..7 (16 rows each)
            const int row = ch * 16 + slr;         // 0..127
            const size_t ga = (size_t)(bm + row) * Dv + k0 + slc;
            const size_t gb = (size_t)(bn + row) * Dv + k0 + slc;
            char* la = (char*)(&Ah[0][0]) + ch * 1024;
            char* lb = (char*)(&Bh[0][0]) + ch * 1024;
            char* la2 = (char*)(&Al[0][0]) + ch * 1024;
            char* lb2 = (char*)(&Bl[0][0]) + ch * 1024;
            gll16(&Xh[ga], la);
            gll16(&Xl[ga], la2);
            gll16(&Wh[gb], lb);
            gll16(&Wl[gb], lb2);
        }
        __syncthreads();

        // ---- fragment reads ----
        h8 a_h[4], a_l[4], b_h[4], b_l[4];
        #pragma unroll
        for (int mf = 0; mf < 4; ++mf) {
            const int r = wr * 64 + mf * 16 + lrow;
            a_h[mf] = *reinterpret_cast<const h8*>(&Ah[r][kg]);
            a_l[mf] = *reinterpret_cast<const h8*>(&Al[r][kg]);
        }
        #pragma unroll
        for (int nf = 0; nf < 4; ++nf) {
            const int c = wc * 64 + nf * 16 + lrow;
            b_h[nf] = *reinterpret_cast<const h8*>(&Bh[c][kg]);
            b_l[nf] = *reinterpret_cast<const h8*>(&Bl[c][kg]);
        }

        // ---- 3-pass split MFMA ----
        #pragma unroll
        for (int mf = 0; mf < 4; ++mf)
            #pragma unroll
            for (int nf = 0; nf < 4; ++nf)
                acc[mf][nf] = __builtin_amdgcn_mfma_f32_16x16x32_f16(a_h[mf], b_h[nf], acc[mf][nf], 0, 0, 0);
        #pragma unroll
        for (int mf = 0; mf < 4; ++mf)
            #pragma unroll
            for (int nf = 0; nf < 4; ++nf)
                acc[mf][nf] = __builtin_amdgcn_mfma_f32_16x16x32_f16(a_h[mf], b_l[nf], acc[mf][nf], 0, 0, 0);
        #pragma unroll
        for (int mf = 0; mf < 4; ++mf)
            #pragma unroll
            for (int nf = 0; nf < 4; ++nf)
                acc[mf][nf] = __builtin_amdgcn_mfma_f32_16x16x32_f16(a_l[mf], b_h[nf], acc[mf][nf], 0, 0, 0);
        __syncthreads();
    }

    // ---- epilogue: bias, /temp, sigmoid ----
    const float invT = 1.0f / scal[0];
    #pragma unroll
    for (int nf = 0; nf < 4; ++nf) {
        const int col = bn + wc * 64 + nf * 16 + lrow;
        if (col >= TN) continue;
        const float bv = bias[col];
        #pragma unroll
        for (int mf = 0; mf < 4; ++mf) {
            #pragma unroll
            for (int r = 0; r < 4; ++r) {
                const int row = bm + wr * 64 + mf * 16 + (lane >> 4) * 4 + r;
                const float z = (acc[mf][nf][r] + bv) * invT;
                S[(size_t)row * TN + col] = 1.0f / (1.0f + __expf(-z));
            }
        }
    }
}

// ---------------------------------------------------------------------------
// mu kernel: per (b,t), 64 leaf path-probs from 63 sigmoids, fold w[t],
// write bf16 (hi only — gemm2 is single-pass bf16).
// ---------------------------------------------------------------------------
__global__ __launch_bounds__(256)
void k_mu(const float* __restrict__ S, const float* __restrict__ scal,
          unsigned short* __restrict__ MH) {
    const int idx = blockIdx.x * 256 + threadIdx.x;
    if (idx >= Bv * Tv) return;
    const int b = idx >> 5;
    const int t = idx & 31;

    const float* sp = S + (size_t)b * TN + t * NI;
    float s[NI];
    #pragma unroll
    for (int i = 0; i < NI; ++i) s[i] = sp[i];

    float mu[NL];
    mu[0] = scal[1 + t];
    #pragma unroll
    for (int d = 0; d < 6; ++d) {
        const int width = 1 << d;
        #pragma unroll
        for (int i = width - 1; i >= 0; --i) {
            const float sv = s[width - 1 + i];
            const float m  = mu[i];
            mu[2 * i + 1] = m * sv;
            mu[2 * i]     = m * (1.0f - sv);
        }
    }

    const size_t base = (size_t)b * TL + t * NL;
    #pragma unroll
    for (int c = 0; c < 8; ++c) {
        us8 vh;
        #pragma unroll
        for (int j = 0; j < 8; ++j) vh[j] = f2bf_rn(mu[c * 8 + j]);
        *reinterpret_cast<us8*>(&MH[base + c * 8]) = vh;
    }
}

// ---------------------------------------------------------------------------
// Leaf softmax: one block per (t,l) row of length C. (writes fp32 P)
// ---------------------------------------------------------------------------
__global__ __launch_bounds__(256)
void k_leafsm(const float* __restrict__ LL, const float* __restrict__ scal,
              float* __restrict__ P) {
    const int r = blockIdx.x;
    const int tid = threadIdx.x;
    const float invT = 1.0f / scal[0];
    const float* row = LL + (size_t)r * Cv;
    float* pr = P + (size_t)r * Cv;
    __shared__ float redm[4];
    __shared__ float reds[4];

    float m = -3.4e38f;
    for (int c = tid; c < Cv; c += 256) m = fmaxf(m, row[c] * invT);
    #pragma unroll
    for (int o = 32; o > 0; o >>= 1) m = fmaxf(m, __shfl_down(m, o));
    if ((tid & 63) == 0) redm[tid >> 6] = m;
    __syncthreads();
    m = fmaxf(fmaxf(redm[0], redm[1]), fmaxf(redm[2], redm[3]));

    float sum = 0.f;
    for (int c = tid; c < Cv; c += 256) {
        const float e = expf(row[c] * invT - m);
        pr[c] = e;
        sum += e;
    }
    #pragma unroll
    for (int o = 32; o > 0; o >>= 1) sum += __shfl_down(sum, o);
    if ((tid & 63) == 0) reds[tid >> 6] = sum;
    __syncthreads();
    sum = reds[0] + reds[1] + reds[2] + reds[3];
    const float rs = 1.0f / sum;
    for (int c = tid; c < Cv; c += 256) pr[c] *= rs;
}

// ---------------------------------------------------------------------------
// Transpose P: fp32 [TL][Cv] -> PTH bf16 [Npad][TL] (rows >= Cv zeroed).
// ---------------------------------------------------------------------------
__global__ __launch_bounds__(256)
void k_tp(const float* __restrict__ P, unsigned short* __restrict__ PTH) {
    __shared__ float T[64][65];
    const int k0 = blockIdx.x * 64;   // leaf (K) tile
    const int c0 = blockIdx.y * 64;   // class tile
    const int tid = threadIdx.x;
    #pragma unroll
    for (int i = 0; i < 16; ++i) {
        const int idx = tid + i * 256;
        const int kk = idx >> 6, cc = idx & 63;
        const int c = c0 + cc;
        T[kk][cc] = (c < Cv) ? P[(size_t)(k0 + kk) * Cv + c] : 0.f;
    }
    __syncthreads();
    #pragma unroll
    for (int i = 0; i < 16; ++i) {
        const int idx = tid + i * 256;
        const int cc = idx >> 6, kk = idx & 63;
        PTH[(size_t)(c0 + cc) * TL + k0 + kk] = f2bf_rn(T[kk][cc]);
    }
}

// ---------------------------------------------------------------------------
// GEMM2 (single-pass bf16 MFMA): out = muw @ P
// A = MH [Bv][TL] bf16, B = PTH [Npad][TL] bf16 (pre-transposed).
// 128x128 tile, BK=32, 4 waves (2x2), wave = 64x64.
// ---------------------------------------------------------------------------
__global__ __launch_bounds__(256, 2)
void k_gemm2(const unsigned short* __restrict__ MH, const unsigned short* __restrict__ PTH,
             float* __restrict__ out) {
    __shared__ unsigned short Ah[128][32];
    __shared__ unsigned short Bh[128][32];

    const int tid  = threadIdx.x;
    const int bm   = blockIdx.y * 128;
    const int bn   = blockIdx.x * 128;
    const int lane = tid & 63;
    const int wv   = tid >> 6;
    const int wr   = wv >> 1;
    const int wc   = wv & 1;
    const int lrow = lane & 15;
    const int kg   = (lane >> 4) * 8;
    const int slr  = lane >> 2;
    const int slc  = (lane & 3) * 8;

    f4v acc[4][4] = {};

    for (int k0 = 0; k0 < TL; k0 += 32) {
        #pragma unroll
        for (int i = 0; i < 2; ++i) {
            const int ch  = wv * 2 + i;
            const int row = ch * 16 + slr;
            gll16(&MH[(size_t)(bm + row) * TL + k0 + slc],
                  (char*)(&Ah[0][0]) + ch * 1024);
            gll16(&PTH[(size_t)(bn + row) * TL + k0 + slc],
                  (char*)(&Bh[0][0]) + ch * 1024);
        }
        __syncthreads();

        s8v a_h[4], b_h[4];
        #pragma unroll
        for (int mf = 0; mf < 4; ++mf) {
            const int r = wr * 64 + mf * 16 + lrow;
            a_h[mf] = *reinterpret_cast<const s8v*>(&Ah[r][kg]);
        }
        #pragma unroll
        for (int nf = 0; nf < 4; ++nf) {
            const int c = wc * 64 + nf * 16 + lrow;
            b_h[nf] = *reinterpret_cast<const s8v*>(&Bh[c][kg]);
        }

        #pragma unroll
        for (int mf = 0; mf < 4; ++mf)
            #pragma unroll
            for (int nf = 0; nf < 4; ++nf)
                acc[mf][nf] = __builtin_amdgcn_mfma_f32_16x16x32_bf16(a_h[mf], b_h[nf], acc[mf][nf], 0, 0, 0);
        __syncthreads();
    }

    #pragma unroll
    for (int nf = 0; nf < 4; ++nf) {
        const int col = bn + wc * 64 + nf * 16 + lrow;
        if (col >= Cv) continue;
        #pragma unroll
        for (int mf = 0; mf < 4; ++mf) {
            #pragma unroll
            for (int r = 0; r < 4; ++r) {
                const int row = bm + wr * 64 + mf * 16 + (lane >> 4) * 4 + r;
                out[(size_t)row * Cv + col] = acc[mf][nf][r];
            }
        }
    }
}

// ---------------------------------------------------------------------------
extern "C" void kernel_launch(void* const* d_in, const int* in_sizes, int n_in,
                              void* d_out, int out_size, void* d_ws, size_t ws_size,
                              hipStream_t stream) {
    const float* x  = (const float*)d_in[0];  // [B, D]
    const float* sw = (const float*)d_in[1];  // [T, NI, D]
    const float* sb = (const float*)d_in[2];  // [T, NI]
    const float* ll = (const float*)d_in[3];  // [T, NL, C]
    const float* tw = (const float*)d_in[4];  // [T]
    const float* lt = (const float*)d_in[5];  // scalar

    float* out  = (float*)d_out;              // [B, C]
    float* ws   = (float*)d_ws;
    float* scal = ws + OFF_SCAL;
    _Float16* Xh = (_Float16*)(ws + OFF_XW);
    _Float16* Xl = Xh + N_X;
    _Float16* Wh = Xl + N_X;
    _Float16* Wl = Wh + N_W;
    float* Sbuf = ws + OFF_S;
    float* Pbuf = ws + OFF_P;
    unsigned short* MH  = (unsigned short*)(ws + OFF_MH);   // aliases X/W splits
    unsigned short* PTH = (unsigned short*)(ws + OFF_PTH);  // aliases S

    k_scalars<<<1, 64, 0, stream>>>(tw, lt, scal);
    k_split<<<(int)(N_X / 4 + 255) / 256, 256, 0, stream>>>(x,  Xh, Xl, (int)N_X, (int)N_X);
    k_split<<<(int)(N_W / 4 + 255) / 256, 256, 0, stream>>>(sw, Wh, Wl, TN * Dv, (int)N_W);
    k_gemm1<<<dim3(16, 32), 256, 0, stream>>>(Xh, Xl, Wh, Wl, sb, scal, Sbuf);
    // k_mu overwrites the X/W split region with MH — gemm1 is done with it (stream order)
    k_mu<<<(Bv * Tv) / 256, 256, 0, stream>>>(Sbuf, scal, MH);
    k_leafsm<<<TL, 256, 0, stream>>>(ll, scal, Pbuf);
    // k_tp overwrites the S region with PTH — k_mu was the last S reader (stream order)
    k_tp<<<dim3(TL / 64, Npad / 64), 256, 0, stream>>>(Pbuf, PTH);
    k_gemm2<<<dim3(Npad / 128, Bv / 128), 256, 0, stream>>>(MH, PTH, out);
}

// Round 5
// 115.013 us; speedup vs baseline: 5.7946x; 1.2740x over previous
//
#include <hip/hip_runtime.h>
#include <cstdint>
#include <cstddef>

// Problem dims
constexpr int Bv = 4096;   // batch
constexpr int Dv = 1024;   // feature dim
constexpr int Cv = 1000;   // classes
constexpr int Tv = 32;     // trees
constexpr int NI = 63;     // internal nodes per tree
constexpr int NL = 64;     // leaves per tree
constexpr int TN = Tv * NI;   // 2016
constexpr int TNp = 2048;     // padded node dim: tree t occupies cols [64t, 64t+63]
constexpr int TL = Tv * NL;   // 2048
constexpr int Npad = 1024;    // padded class dim

typedef _Float16 h8  __attribute__((ext_vector_type(8)));
typedef _Float16 h4  __attribute__((ext_vector_type(4)));
typedef short    s8v __attribute__((ext_vector_type(8)));
typedef unsigned short us8 __attribute__((ext_vector_type(8)));
typedef float    f4v __attribute__((ext_vector_type(4)));

// ---------------------------------------------------------------------------
// Workspace layout (float units). No aliasing needed: total ~60.5 MB
// (round-3/4 proved >= 66 MB available).
// ---------------------------------------------------------------------------
constexpr size_t OFF_SCAL = 0;                                   // 64 floats
constexpr size_t N_X   = (size_t)Bv * Dv;                        // 4M elems
constexpr size_t N_W   = (size_t)TNp * Dv;                       // 2M elems (padded)
constexpr size_t OFF_XH = 64;                                    // f16 [Bv][Dv]
constexpr size_t OFF_WH = OFF_XH + N_X / 2;                      // f16 [TNp][Dv]
constexpr size_t OFF_WL = OFF_WH + N_W / 2;                      // f16 [TNp][Dv]
constexpr size_t OFF_S  = OFF_WL + N_W / 2;                      // f16 [Bv][TNp]
constexpr size_t OFF_P  = OFF_S + (size_t)Bv * TNp / 2;          // fp32 [TL][Cv]
constexpr size_t OFF_MH = OFF_P + (size_t)TL * Cv;               // bf16 [Bv][TL]
constexpr size_t OFF_PTH= OFF_MH + (size_t)Bv * TL / 2;          // bf16 [Npad][TL]

// bf16 round-to-nearest-even from fp32
__device__ __forceinline__ unsigned short f2bf_rn(float x) {
    unsigned u = __float_as_uint(x);
    return (unsigned short)((u + 0x7fffu + ((u >> 16) & 1u)) >> 16);
}

// async global->LDS, 16B per lane, LDS dest = wave-uniform base + lane*16
__device__ __forceinline__ void gll16(const void* gptr, void* lptr) {
    __builtin_amdgcn_global_load_lds(
        (const __attribute__((address_space(1))) unsigned int*)gptr,
        (__attribute__((address_space(3))) unsigned int*)lptr,
        16, 0, 0);
}

// ---------------------------------------------------------------------------
// Scalars
// ---------------------------------------------------------------------------
__global__ void k_scalars(const float* __restrict__ tw, const float* __restrict__ lt,
                          float* __restrict__ scal) {
    if (threadIdx.x == 0) {
        float temp = fminf(fmaxf(expf(lt[0]), 0.1f), 5.0f);
        scal[0] = temp;
        float m = -3.4e38f;
        for (int t = 0; t < Tv; ++t) m = fmaxf(m, tw[t]);
        float s = 0.f;
        for (int t = 0; t < Tv; ++t) { float e = expf(tw[t] - m); scal[1 + t] = e; s += e; }
        float inv = 1.0f / s;
        for (int t = 0; t < Tv; ++t) scal[1 + t] *= inv;
    }
}

// ---------------------------------------------------------------------------
// X split: fp32 -> f16 hi only (2-pass GEMM1 drops x-lo term)
// ---------------------------------------------------------------------------
__global__ __launch_bounds__(256)
void k_split_x(const float* __restrict__ src, _Float16* __restrict__ hi) {
    const size_t i4 = ((size_t)blockIdx.x * 256 + threadIdx.x) * 4;
    if (i4 >= N_X) return;
    const float4 v = *reinterpret_cast<const float4*>(&src[i4]);
    h4 vh;
    vh[0] = (_Float16)v.x; vh[1] = (_Float16)v.y;
    vh[2] = (_Float16)v.z; vh[3] = (_Float16)v.w;
    *reinterpret_cast<h4*>(&hi[i4]) = vh;
}

// ---------------------------------------------------------------------------
// W split with per-tree row padding: src row (t*63+i) -> dst row (t*64+i),
// dst rows with i==63 zeroed. f16 hi + lo.
// ---------------------------------------------------------------------------
__global__ __launch_bounds__(256)
void k_split_w(const float* __restrict__ sw, _Float16* __restrict__ Wh,
               _Float16* __restrict__ Wl) {
    const size_t d4 = ((size_t)blockIdx.x * 256 + threadIdx.x) * 4;
    if (d4 >= N_W) return;
    const int row = (int)(d4 >> 10);
    const int col = (int)(d4 & 1023);
    const int t = row >> 6, i = row & 63;
    float4 v = make_float4(0.f, 0.f, 0.f, 0.f);
    if (i < NI) v = *reinterpret_cast<const float4*>(&sw[((size_t)(t * NI + i)) * Dv + col]);
    h4 vh, vl;
    _Float16 h;
    h = (_Float16)v.x; vh[0] = h; vl[0] = (_Float16)(v.x - (float)h);
    h = (_Float16)v.y; vh[1] = h; vl[1] = (_Float16)(v.y - (float)h);
    h = (_Float16)v.z; vh[2] = h; vl[2] = (_Float16)(v.z - (float)h);
    h = (_Float16)v.w; vh[3] = h; vl[3] = (_Float16)(v.w - (float)h);
    *reinterpret_cast<h4*>(&Wh[d4]) = vh;
    *reinterpret_cast<h4*>(&Wl[d4]) = vl;
}

// ---------------------------------------------------------------------------
// GEMM1 (NT, 2-pass f16 split): S = sigmoid((x @ W^T + bias)/temp), S in f16.
// 128x128 tile, BK=32, 4 waves (2x2), double-buffered LDS, counted vmcnt.
// acc += Xh*Wh + Xh*Wl  (error = x_lo * w, ~5e-4 on logits -- analyzed safe)
// ---------------------------------------------------------------------------
__global__ __launch_bounds__(256, 2)
void k_gemm1(const _Float16* __restrict__ Xh, const _Float16* __restrict__ Wh,
             const _Float16* __restrict__ Wl, const float* __restrict__ bias,
             const float* __restrict__ scal, _Float16* __restrict__ S) {
    __shared__ _Float16 L[2][3][128][32];   // [buf][slab: X,Wh,Wl] -> 48 KB

    const int tid  = threadIdx.x;
    const int bm   = blockIdx.y * 128;
    const int bn   = blockIdx.x * 128;
    const int lane = tid & 63;
    const int wv   = tid >> 6;
    const int wr   = wv >> 1;
    const int wc   = wv & 1;
    const int lrow = lane & 15;
    const int kg   = (lane >> 4) * 8;
    const int sr   = lane >> 2;        // staging row within 16-row chunk
    const int sc   = (lane & 3) * 8;   // staging f16 col

    f4v acc[4][4] = {};

    // 6 gll16 issues per wave per tile
#define STAGE1(bufi, k0)                                                          \
    { _Pragma("unroll")                                                           \
      for (int i_ = 0; i_ < 2; ++i_) {                                            \
        const int ch_  = wv * 2 + i_;                                             \
        const int row_ = ch_ * 16 + sr;                                           \
        gll16(&Xh[(size_t)(bm + row_) * Dv + (k0) + sc],                          \
              (char*)&L[bufi][0][0][0] + ch_ * 1024);                             \
        gll16(&Wh[(size_t)(bn + row_) * Dv + (k0) + sc],                          \
              (char*)&L[bufi][1][0][0] + ch_ * 1024);                             \
        gll16(&Wl[(size_t)(bn + row_) * Dv + (k0) + sc],                          \
              (char*)&L[bufi][2][0][0] + ch_ * 1024);                             \
      } }

    STAGE1(0, 0);
    for (int t = 0; t < 32; ++t) {
        const int cur = t & 1;
        if (t < 31) {
            STAGE1(cur ^ 1, (t + 1) * 32);
            asm volatile("s_waitcnt vmcnt(6)" ::: "memory");  // current tile's 6 done
        } else {
            asm volatile("s_waitcnt vmcnt(0)" ::: "memory");
        }
        __builtin_amdgcn_s_barrier();
        __builtin_amdgcn_sched_barrier(0);

        h8 a[4], bh[4], bl[4];
        #pragma unroll
        for (int mf = 0; mf < 4; ++mf)
            a[mf] = *reinterpret_cast<const h8*>(&L[cur][0][wr * 64 + mf * 16 + lrow][kg]);
        #pragma unroll
        for (int nf = 0; nf < 4; ++nf) {
            bh[nf] = *reinterpret_cast<const h8*>(&L[cur][1][wc * 64 + nf * 16 + lrow][kg]);
            bl[nf] = *reinterpret_cast<const h8*>(&L[cur][2][wc * 64 + nf * 16 + lrow][kg]);
        }
        #pragma unroll
        for (int mf = 0; mf < 4; ++mf)
            #pragma unroll
            for (int nf = 0; nf < 4; ++nf)
                acc[mf][nf] = __builtin_amdgcn_mfma_f32_16x16x32_f16(a[mf], bh[nf], acc[mf][nf], 0, 0, 0);
        #pragma unroll
        for (int mf = 0; mf < 4; ++mf)
            #pragma unroll
            for (int nf = 0; nf < 4; ++nf)
                acc[mf][nf] = __builtin_amdgcn_mfma_f32_16x16x32_f16(a[mf], bl[nf], acc[mf][nf], 0, 0, 0);

        __builtin_amdgcn_sched_barrier(0);
        asm volatile("s_waitcnt lgkmcnt(0)" ::: "memory");  // our ds_reads done
        __builtin_amdgcn_s_barrier();                        // safe to overwrite cur next iter
    }
#undef STAGE1

    // epilogue: bias (remapped), /temp, sigmoid, store f16 (padded cols)
    const float invT = 1.0f / scal[0];
    #pragma unroll
    for (int nf = 0; nf < 4; ++nf) {
        const int col = bn + wc * 64 + nf * 16 + lrow;   // 0..2047 (padded)
        const int tt = col >> 6, ii = col & 63;
        const float bv = (ii < NI) ? bias[tt * NI + ii] : 0.f;
        #pragma unroll
        for (int mf = 0; mf < 4; ++mf) {
            #pragma unroll
            for (int r = 0; r < 4; ++r) {
                const int row = bm + wr * 64 + mf * 16 + (lane >> 4) * 4 + r;
                const float z = (acc[mf][nf][r] + bv) * invT;
                S[(size_t)row * TNp + col] = (_Float16)(1.0f / (1.0f + __expf(-z)));
            }
        }
    }
}

// ---------------------------------------------------------------------------
// mu kernel: reads padded f16 S (tree t at cols [64t,64t+63]), folds w[t],
// writes bf16 MH.
// ---------------------------------------------------------------------------
__global__ __launch_bounds__(256)
void k_mu(const _Float16* __restrict__ S, const float* __restrict__ scal,
          unsigned short* __restrict__ MH) {
    const int idx = blockIdx.x * 256 + threadIdx.x;
    if (idx >= Bv * Tv) return;
    const int b = idx >> 5;
    const int t = idx & 31;

    const _Float16* sp = S + (size_t)b * TNp + t * 64;
    h8 v[8];
    #pragma unroll
    for (int c = 0; c < 8; ++c) v[c] = *reinterpret_cast<const h8*>(&sp[c * 8]);
    float s[NI];
    #pragma unroll
    for (int i = 0; i < NI; ++i) s[i] = (float)v[i >> 3][i & 7];

    float mu[NL];
    mu[0] = scal[1 + t];
    #pragma unroll
    for (int d = 0; d < 6; ++d) {
        const int width = 1 << d;
        #pragma unroll
        for (int i = width - 1; i >= 0; --i) {
            const float sv = s[width - 1 + i];
            const float m  = mu[i];
            mu[2 * i + 1] = m * sv;
            mu[2 * i]     = m * (1.0f - sv);
        }
    }

    const size_t base = (size_t)b * TL + t * NL;
    #pragma unroll
    for (int c = 0; c < 8; ++c) {
        us8 vh;
        #pragma unroll
        for (int j = 0; j < 8; ++j) vh[j] = f2bf_rn(mu[c * 8 + j]);
        *reinterpret_cast<us8*>(&MH[base + c * 8]) = vh;
    }
}

// ---------------------------------------------------------------------------
// Leaf softmax (fp32 P)
// ---------------------------------------------------------------------------
__global__ __launch_bounds__(256)
void k_leafsm(const float* __restrict__ LL, const float* __restrict__ scal,
              float* __restrict__ P) {
    const int r = blockIdx.x;
    const int tid = threadIdx.x;
    const float invT = 1.0f / scal[0];
    const float* row = LL + (size_t)r * Cv;
    float* pr = P + (size_t)r * Cv;
    __shared__ float redm[4];
    __shared__ float reds[4];

    float m = -3.4e38f;
    for (int c = tid; c < Cv; c += 256) m = fmaxf(m, row[c] * invT);
    #pragma unroll
    for (int o = 32; o > 0; o >>= 1) m = fmaxf(m, __shfl_down(m, o));
    if ((tid & 63) == 0) redm[tid >> 6] = m;
    __syncthreads();
    m = fmaxf(fmaxf(redm[0], redm[1]), fmaxf(redm[2], redm[3]));

    float sum = 0.f;
    for (int c = tid; c < Cv; c += 256) {
        const float e = expf(row[c] * invT - m);
        pr[c] = e;
        sum += e;
    }
    #pragma unroll
    for (int o = 32; o > 0; o >>= 1) sum += __shfl_down(sum, o);
    if ((tid & 63) == 0) reds[tid >> 6] = sum;
    __syncthreads();
    sum = reds[0] + reds[1] + reds[2] + reds[3];
    const float rs = 1.0f / sum;
    for (int c = tid; c < Cv; c += 256) pr[c] *= rs;
}

// ---------------------------------------------------------------------------
// Transpose P: fp32 [TL][Cv] -> PTH bf16 [Npad][TL] (rows >= Cv zeroed)
// ---------------------------------------------------------------------------
__global__ __launch_bounds__(256)
void k_tp(const float* __restrict__ P, unsigned short* __restrict__ PTH) {
    __shared__ float T[64][65];
    const int k0 = blockIdx.x * 64;
    const int c0 = blockIdx.y * 64;
    const int tid = threadIdx.x;
    #pragma unroll
    for (int i = 0; i < 16; ++i) {
        const int idx = tid + i * 256;
        const int kk = idx >> 6, cc = idx & 63;
        const int c = c0 + cc;
        T[kk][cc] = (c < Cv) ? P[(size_t)(k0 + kk) * Cv + c] : 0.f;
    }
    __syncthreads();
    #pragma unroll
    for (int i = 0; i < 16; ++i) {
        const int idx = tid + i * 256;
        const int cc = idx >> 6, kk = idx & 63;
        PTH[(size_t)(c0 + cc) * TL + k0 + kk] = f2bf_rn(T[kk][cc]);
    }
}

// ---------------------------------------------------------------------------
// GEMM2 (single-pass bf16): out = muw @ P. A = MH [Bv][TL], B = PTH [Npad][TL].
// 128x64 tile (grid 512 = 2 blocks/CU), K-step 64 as two 32-sub-steps,
// double-buffered LDS, counted vmcnt. 4 waves (2x2), wave = 64x32.
// ---------------------------------------------------------------------------
__global__ __launch_bounds__(256, 2)
void k_gemm2(const unsigned short* __restrict__ MH, const unsigned short* __restrict__ PTH,
             float* __restrict__ out) {
    __shared__ unsigned short LA[2][2][128][32];   // 32 KB
    __shared__ unsigned short LB[2][2][64][32];    // 16 KB

    const int tid  = threadIdx.x;
    const int bm   = blockIdx.y * 128;
    const int bn   = blockIdx.x * 64;
    const int lane = tid & 63;
    const int wv   = tid >> 6;
    const int wr   = wv >> 1;
    const int wc   = wv & 1;
    const int lrow = lane & 15;
    const int kg   = (lane >> 4) * 8;
    const int sr   = lane >> 2;
    const int sc   = (lane & 3) * 8;

    f4v acc[4][2] = {};

    // 6 gll16 issues per wave per tile (2xA + 1xB per K-half)
#define STAGE2(bufi, k0)                                                          \
    { _Pragma("unroll")                                                           \
      for (int kh_ = 0; kh_ < 2; ++kh_) {                                         \
        _Pragma("unroll")                                                         \
        for (int i_ = 0; i_ < 2; ++i_) {                                          \
          const int ch_  = wv * 2 + i_;                                           \
          const int row_ = ch_ * 16 + sr;                                         \
          gll16(&MH[(size_t)(bm + row_) * TL + (k0) + kh_ * 32 + sc],             \
                (char*)&LA[bufi][kh_][0][0] + ch_ * 1024);                        \
        }                                                                         \
        { const int row_ = wv * 16 + sr;                                          \
          gll16(&PTH[(size_t)(bn + row_) * TL + (k0) + kh_ * 32 + sc],            \
                (char*)&LB[bufi][kh_][0][0] + wv * 1024); }                       \
      } }

    STAGE2(0, 0);
    for (int t = 0; t < 32; ++t) {
        const int cur = t & 1;
        if (t < 31) {
            STAGE2(cur ^ 1, (t + 1) * 64);
            asm volatile("s_waitcnt vmcnt(6)" ::: "memory");
        } else {
            asm volatile("s_waitcnt vmcnt(0)" ::: "memory");
        }
        __builtin_amdgcn_s_barrier();
        __builtin_amdgcn_sched_barrier(0);

        #pragma unroll
        for (int kh = 0; kh < 2; ++kh) {
            s8v a[4], b[2];
            #pragma unroll
            for (int mf = 0; mf < 4; ++mf)
                a[mf] = *reinterpret_cast<const s8v*>(&LA[cur][kh][wr * 64 + mf * 16 + lrow][kg]);
            #pragma unroll
            for (int nf = 0; nf < 2; ++nf)
                b[nf] = *reinterpret_cast<const s8v*>(&LB[cur][kh][wc * 32 + nf * 16 + lrow][kg]);
            #pragma unroll
            for (int mf = 0; mf < 4; ++mf)
                #pragma unroll
                for (int nf = 0; nf < 2; ++nf)
                    acc[mf][nf] = __builtin_amdgcn_mfma_f32_16x16x32_bf16(a[mf], b[nf], acc[mf][nf], 0, 0, 0);
        }

        __builtin_amdgcn_sched_barrier(0);
        asm volatile("s_waitcnt lgkmcnt(0)" ::: "memory");
        __builtin_amdgcn_s_barrier();
    }
#undef STAGE2

    #pragma unroll
    for (int nf = 0; nf < 2; ++nf) {
        const int col = bn + wc * 32 + nf * 16 + lrow;
        if (col >= Cv) continue;
        #pragma unroll
        for (int mf = 0; mf < 4; ++mf) {
            #pragma unroll
            for (int r = 0; r < 4; ++r) {
                const int row = bm + wr * 64 + mf * 16 + (lane >> 4) * 4 + r;
                out[(size_t)row * Cv + col] = acc[mf][nf][r];
            }
        }
    }
}

// ---------------------------------------------------------------------------
extern "C" void kernel_launch(void* const* d_in, const int* in_sizes, int n_in,
                              void* d_out, int out_size, void* d_ws, size_t ws_size,
                              hipStream_t stream) {
    const float* x  = (const float*)d_in[0];  // [B, D]
    const float* sw = (const float*)d_in[1];  // [T, NI, D]
    const float* sb = (const float*)d_in[2];  // [T, NI]
    const float* ll = (const float*)d_in[3];  // [T, NL, C]
    const float* tw = (const float*)d_in[4];  // [T]
    const float* lt = (const float*)d_in[5];  // scalar

    float* out  = (float*)d_out;              // [B, C]
    float* ws   = (float*)d_ws;
    float* scal = ws + OFF_SCAL;
    _Float16* Xh = (_Float16*)(ws + OFF_XH);
    _Float16* Wh = (_Float16*)(ws + OFF_WH);
    _Float16* Wl = (_Float16*)(ws + OFF_WL);
    _Float16* Sb = (_Float16*)(ws + OFF_S);
    float* Pbuf = ws + OFF_P;
    unsigned short* MH  = (unsigned short*)(ws + OFF_MH);
    unsigned short* PTH = (unsigned short*)(ws + OFF_PTH);

    k_scalars<<<1, 64, 0, stream>>>(tw, lt, scal);
    k_split_x<<<(int)(N_X / 4 / 256), 256, 0, stream>>>(x, Xh);
    k_split_w<<<(int)(N_W / 4 / 256), 256, 0, stream>>>(sw, Wh, Wl);
    k_gemm1<<<dim3(TNp / 128, Bv / 128), 256, 0, stream>>>(Xh, Wh, Wl, sb, scal, Sb);
    k_mu<<<(Bv * Tv) / 256, 256, 0, stream>>>(Sb, scal, MH);
    k_leafsm<<<TL, 256, 0, stream>>>(ll, scal, Pbuf);
    k_tp<<<dim3(TL / 64, Npad / 64), 256, 0, stream>>>(Pbuf, PTH);
    k_gemm2<<<dim3(Npad / 64, Bv / 128), 256, 0, stream>>>(MH, PTH, out);
}

// Round 6
// 89.331 us; speedup vs baseline: 7.4605x; 1.2875x over previous
//
#include <hip/hip_runtime.h>
#include <cstdint>
#include <cstddef>

// Problem dims
constexpr int Bv = 4096;   // batch
constexpr int Dv = 1024;   // feature dim
constexpr int Cv = 1000;   // classes
constexpr int Tv = 32;     // trees
constexpr int NI = 63;     // internal nodes per tree
constexpr int NL = 64;     // leaves per tree
constexpr int TNp = 2048;  // padded node dim: tree t at cols [64t, 64t+63]
constexpr int TL = Tv * NL;   // 2048
constexpr int Npad = 1024;    // padded class dim

typedef _Float16 h8  __attribute__((ext_vector_type(8)));
typedef _Float16 h4  __attribute__((ext_vector_type(4)));
typedef short    s8v __attribute__((ext_vector_type(8)));
typedef unsigned short us8 __attribute__((ext_vector_type(8)));
typedef float    f4v __attribute__((ext_vector_type(4)));

// ---------------------------------------------------------------------------
// Workspace layout (float units). Total ~40.5 MB.
// ---------------------------------------------------------------------------
constexpr size_t N_X    = (size_t)Bv * Dv;                 // 4M elems
constexpr size_t N_W    = (size_t)TNp * Dv;                // 2M elems (padded)
constexpr size_t OFF_XH = 64;                              // f16 [Bv][Dv]
constexpr size_t OFF_WH = OFF_XH + N_X / 2;                // f16 [TNp][Dv]
constexpr size_t OFF_P  = OFF_WH + N_W / 2;                // fp32 [TL][Cv]
constexpr size_t OFF_MH = OFF_P + (size_t)TL * Cv;         // bf16 [Bv][TL]
constexpr size_t OFF_PTH= OFF_MH + (size_t)Bv * TL / 2;    // bf16 [Npad][TL]

// bf16 round-to-nearest-even from fp32
__device__ __forceinline__ unsigned short f2bf_rn(float x) {
    unsigned u = __float_as_uint(x);
    return (unsigned short)((u + 0x7fffu + ((u >> 16) & 1u)) >> 16);
}

// async global->LDS, 16B per lane, LDS dest = wave-uniform base + lane*16
__device__ __forceinline__ void gll16(const void* gptr, void* lptr) {
    __builtin_amdgcn_global_load_lds(
        (const __attribute__((address_space(1))) unsigned int*)gptr,
        (__attribute__((address_space(3))) unsigned int*)lptr,
        16, 0, 0);
}

// ---------------------------------------------------------------------------
// Fused input prep: blocks [0, N_X/1024) cast x -> f16 hi; the rest re-pack
// W rows (t*63+i) -> padded rows (t*64+i) as f16 hi (row i==63 zeroed).
// Single-pass f16 GEMM1: lo parts dropped (noise analyzed: ~1.2e-3 rms logits).
// ---------------------------------------------------------------------------
__global__ __launch_bounds__(256)
void k_prep(const float* __restrict__ x, const float* __restrict__ sw,
            _Float16* __restrict__ Xh, _Float16* __restrict__ Wh) {
    const int b = blockIdx.x;
    const int tid = threadIdx.x;
    const int nbx = (int)(N_X / 1024);
    if (b < nbx) {
        const size_t i4 = ((size_t)b * 256 + tid) * 4;
        const float4 v = *reinterpret_cast<const float4*>(&x[i4]);
        h4 vh;
        vh[0] = (_Float16)v.x; vh[1] = (_Float16)v.y;
        vh[2] = (_Float16)v.z; vh[3] = (_Float16)v.w;
        *reinterpret_cast<h4*>(&Xh[i4]) = vh;
    } else {
        const size_t d4 = ((size_t)(b - nbx) * 256 + tid) * 4;
        const int row = (int)(d4 >> 10);
        const int col = (int)(d4 & 1023);
        const int t = row >> 6, i = row & 63;
        float4 v = make_float4(0.f, 0.f, 0.f, 0.f);
        if (i < NI)
            v = *reinterpret_cast<const float4*>(&sw[(size_t)(t * NI + i) * Dv + col]);
        h4 vh;
        vh[0] = (_Float16)v.x; vh[1] = (_Float16)v.y;
        vh[2] = (_Float16)v.z; vh[3] = (_Float16)v.w;
        *reinterpret_cast<h4*>(&Wh[d4]) = vh;
    }
}

// ---------------------------------------------------------------------------
// GEMM1+mu fused: logits = Xh @ Wh^T (single f16 pass), sigmoid in fp32,
// per-wave LDS transpose, per-lane tree path-product with w[t] folded,
// writes MH bf16 [Bv][TL] directly. S buffer eliminated.
// 128x128 tile = 2 full trees; wave (wr,wc) owns 64 rows x tree (2bx+wc).
// Double-buffered LDS staging via global_load_lds, counted vmcnt(4).
// ---------------------------------------------------------------------------
__global__ __launch_bounds__(256, 2)
void k_gemm1mu(const _Float16* __restrict__ Xh, const _Float16* __restrict__ Wh,
               const float* __restrict__ bias, const float* __restrict__ tw,
               const float* __restrict__ lt, unsigned short* __restrict__ MH) {
    // staging (2buf x 2slab x 128x32 f16 = 32 KB) overlapped with epilogue
    // scratch (4 waves x [64][65] f32 = 66,560 B)
    __shared__ __align__(16) char lds[4 * 64 * 65 * 4];

    const int tid = threadIdx.x;
    // XCD swizzle: 512 wgs, 8 chunks of 64 = 16(by) x 4(bx) tile sub-blocks
    const int wg  = (blockIdx.x & 7) * 64 + (blockIdx.x >> 3);
    const int blk = wg >> 6;                       // 0..7
    const int j   = wg & 63;
    const int bx  = (blk & 3) * 4 + (j & 3);       // 0..15
    const int by  = (blk >> 2) * 16 + (j >> 2);    // 0..31
    const int bm = by * 128, bn = bx * 128;

    const int lane = tid & 63, wv = tid >> 6;
    const int wr = wv >> 1, wc = wv & 1;
    const int lrow = lane & 15, kg = (lane >> 4) * 8;
    const int sr = lane >> 2, sc = (lane & 3) * 8;

    // scalars (inline; k_scalars kernel eliminated)
    const float temp = fminf(fmaxf(expf(lt[0]), 0.1f), 5.0f);
    const float invT = 1.0f / temp;
    const int mytree = 2 * bx + wc;
    float wm = -3.4e38f;
    #pragma unroll
    for (int t = 0; t < Tv; ++t) wm = fmaxf(wm, tw[t]);
    float wsum = 0.f, wmine = 0.f;
    #pragma unroll
    for (int t = 0; t < Tv; ++t) {
        const float e = expf(tw[t] - wm);
        wsum += e;
        if (t == mytree) wmine = e;
    }
    const float wt = wmine / wsum;

    f4v acc[4][4] = {};

    // 4 gll16 issues per wave per tile (2 chunks x 2 slabs)
#define STG(bufi, k0)                                                         \
    { _Pragma("unroll")                                                       \
      for (int i_ = 0; i_ < 2; ++i_) {                                        \
        const int ch_  = wv * 2 + i_;                                         \
        const int row_ = ch_ * 16 + sr;                                       \
        gll16(&Xh[(size_t)(bm + row_) * Dv + (k0) + sc],                      \
              lds + (bufi) * 16384 + ch_ * 1024);                             \
        gll16(&Wh[(size_t)(bn + row_) * Dv + (k0) + sc],                      \
              lds + (bufi) * 16384 + 8192 + ch_ * 1024);                      \
      } }

    STG(0, 0);
    for (int t = 0; t < 32; ++t) {
        const int cur = t & 1;
        if (t < 31) {
            STG(cur ^ 1, (t + 1) * 32);
            asm volatile("s_waitcnt vmcnt(4)" ::: "memory");
        } else {
            asm volatile("s_waitcnt vmcnt(0)" ::: "memory");
        }
        __builtin_amdgcn_s_barrier();
        __builtin_amdgcn_sched_barrier(0);

        h8 a[4], b[4];
        #pragma unroll
        for (int mf = 0; mf < 4; ++mf)
            a[mf] = *reinterpret_cast<const h8*>(
                lds + cur * 16384 + (wr * 64 + mf * 16 + lrow) * 64 + kg * 2);
        #pragma unroll
        for (int nf = 0; nf < 4; ++nf)
            b[nf] = *reinterpret_cast<const h8*>(
                lds + cur * 16384 + 8192 + (wc * 64 + nf * 16 + lrow) * 64 + kg * 2);
        #pragma unroll
        for (int mf = 0; mf < 4; ++mf)
            #pragma unroll
            for (int nf = 0; nf < 4; ++nf)
                acc[mf][nf] = __builtin_amdgcn_mfma_f32_16x16x32_f16(a[mf], b[nf], acc[mf][nf], 0, 0, 0);

        __builtin_amdgcn_sched_barrier(0);
        asm volatile("s_waitcnt lgkmcnt(0)" ::: "memory");
        __builtin_amdgcn_s_barrier();   // after this, staging LDS is reusable
    }
#undef STG

    // ---- epilogue: sigmoid -> per-wave [64 rows][65] f32 scratch ----
    float* scr = (float*)lds + wv * (64 * 65);
    #pragma unroll
    for (int nf = 0; nf < 4; ++nf) {
        const int colB = nf * 16 + lrow;                 // node idx 0..63
        const int gcol = bn + wc * 64 + colB;
        const int ii = gcol & 63;
        const float bv = (ii < NI) ? bias[(gcol >> 6) * NI + ii] : 0.f;
        #pragma unroll
        for (int mf = 0; mf < 4; ++mf) {
            #pragma unroll
            for (int r = 0; r < 4; ++r) {
                const int rowB = mf * 16 + (lane >> 4) * 4 + r;
                const float z = (acc[mf][nf][r] + bv) * invT;
                scr[rowB * 65 + colB] = 1.0f / (1.0f + __expf(-z));
            }
        }
    }
    asm volatile("s_waitcnt lgkmcnt(0)" ::: "memory");   // wave-local writes done

    // ---- per-lane mu: row = lane, tree = mytree; s read from LDS ----
    const float* srow = scr + lane * 65;
    float mu[NL];
    mu[0] = wt;
    #pragma unroll
    for (int d = 0; d < 6; ++d) {
        const int width = 1 << d;
        #pragma unroll
        for (int i = width - 1; i >= 0; --i) {
            const float sv = srow[width - 1 + i];
            const float m  = mu[i];
            mu[2 * i + 1] = m * sv;
            mu[2 * i]     = m * (1.0f - sv);
        }
    }
    const size_t obase = (size_t)(bm + wr * 64 + lane) * TL + (size_t)mytree * 64;
    #pragma unroll
    for (int c = 0; c < 8; ++c) {
        us8 vh;
        #pragma unroll
        for (int jj = 0; jj < 8; ++jj) vh[jj] = f2bf_rn(mu[c * 8 + jj]);
        *reinterpret_cast<us8*>(&MH[obase + c * 8]) = vh;
    }
}

// ---------------------------------------------------------------------------
// Leaf softmax (fp32 P), temp inlined
// ---------------------------------------------------------------------------
__global__ __launch_bounds__(256)
void k_leafsm(const float* __restrict__ LL, const float* __restrict__ lt,
              float* __restrict__ P) {
    const int r = blockIdx.x;
    const int tid = threadIdx.x;
    const float temp = fminf(fmaxf(expf(lt[0]), 0.1f), 5.0f);
    const float invT = 1.0f / temp;
    const float* row = LL + (size_t)r * Cv;
    float* pr = P + (size_t)r * Cv;
    __shared__ float redm[4];
    __shared__ float reds[4];

    float m = -3.4e38f;
    for (int c = tid; c < Cv; c += 256) m = fmaxf(m, row[c] * invT);
    #pragma unroll
    for (int o = 32; o > 0; o >>= 1) m = fmaxf(m, __shfl_down(m, o));
    if ((tid & 63) == 0) redm[tid >> 6] = m;
    __syncthreads();
    m = fmaxf(fmaxf(redm[0], redm[1]), fmaxf(redm[2], redm[3]));

    float sum = 0.f;
    for (int c = tid; c < Cv; c += 256) {
        const float e = expf(row[c] * invT - m);
        pr[c] = e;
        sum += e;
    }
    #pragma unroll
    for (int o = 32; o > 0; o >>= 1) sum += __shfl_down(sum, o);
    if ((tid & 63) == 0) reds[tid >> 6] = sum;
    __syncthreads();
    sum = reds[0] + reds[1] + reds[2] + reds[3];
    const float rs = 1.0f / sum;
    for (int c = tid; c < Cv; c += 256) pr[c] *= rs;
}

// ---------------------------------------------------------------------------
// Transpose P: fp32 [TL][Cv] -> PTH bf16 [Npad][TL] (rows >= Cv zeroed)
// ---------------------------------------------------------------------------
__global__ __launch_bounds__(256)
void k_tp(const float* __restrict__ P, unsigned short* __restrict__ PTH) {
    __shared__ float T[64][65];
    const int k0 = blockIdx.x * 64;
    const int c0 = blockIdx.y * 64;
    const int tid = threadIdx.x;
    #pragma unroll
    for (int i = 0; i < 16; ++i) {
        const int idx = tid + i * 256;
        const int kk = idx >> 6, cc = idx & 63;
        const int c = c0 + cc;
        T[kk][cc] = (c < Cv) ? P[(size_t)(k0 + kk) * Cv + c] : 0.f;
    }
    __syncthreads();
    #pragma unroll
    for (int i = 0; i < 16; ++i) {
        const int idx = tid + i * 256;
        const int cc = idx >> 6, kk = idx & 63;
        PTH[(size_t)(c0 + cc) * TL + k0 + kk] = f2bf_rn(T[kk][cc]);
    }
}

// ---------------------------------------------------------------------------
// GEMM2 (single-pass bf16): out = muw @ P. A = MH [Bv][TL], B = PTH [Npad][TL].
// 128x64 tile, K-step 64 (two 32-sub-steps), double-buffered, counted vmcnt.
// XCD swizzle: chunks of 64 = 8(bm) x 8(bn) sub-blocks.
// ---------------------------------------------------------------------------
__global__ __launch_bounds__(256, 2)
void k_gemm2(const unsigned short* __restrict__ MH, const unsigned short* __restrict__ PTH,
             float* __restrict__ out) {
    __shared__ unsigned short LA[2][2][128][32];   // 32 KB
    __shared__ unsigned short LB[2][2][64][32];    // 16 KB

    const int tid  = threadIdx.x;
    const int wg  = (blockIdx.x & 7) * 64 + (blockIdx.x >> 3);
    const int blk = wg >> 6;                        // 0..7
    const int j   = wg & 63;
    const int bnt = (blk & 1) * 8 + (j & 7);        // 0..15
    const int bmt = (blk >> 1) * 8 + (j >> 3);      // 0..31
    const int bm = bmt * 128, bn = bnt * 64;

    const int lane = tid & 63;
    const int wv   = tid >> 6;
    const int wr   = wv >> 1;
    const int wc   = wv & 1;
    const int lrow = lane & 15;
    const int kg   = (lane >> 4) * 8;
    const int sr   = lane >> 2;
    const int sc   = (lane & 3) * 8;

    f4v acc[4][2] = {};

#define STAGE2(bufi, k0)                                                          \
    { _Pragma("unroll")                                                           \
      for (int kh_ = 0; kh_ < 2; ++kh_) {                                         \
        _Pragma("unroll")                                                         \
        for (int i_ = 0; i_ < 2; ++i_) {                                          \
          const int ch_  = wv * 2 + i_;                                           \
          const int row_ = ch_ * 16 + sr;                                         \
          gll16(&MH[(size_t)(bm + row_) * TL + (k0) + kh_ * 32 + sc],             \
                (char*)&LA[bufi][kh_][0][0] + ch_ * 1024);                        \
        }                                                                         \
        { const int row_ = wv * 16 + sr;                                          \
          gll16(&PTH[(size_t)(bn + row_) * TL + (k0) + kh_ * 32 + sc],            \
                (char*)&LB[bufi][kh_][0][0] + wv * 1024); }                       \
      } }

    STAGE2(0, 0);
    for (int t = 0; t < 32; ++t) {
        const int cur = t & 1;
        if (t < 31) {
            STAGE2(cur ^ 1, (t + 1) * 64);
            asm volatile("s_waitcnt vmcnt(6)" ::: "memory");
        } else {
            asm volatile("s_waitcnt vmcnt(0)" ::: "memory");
        }
        __builtin_amdgcn_s_barrier();
        __builtin_amdgcn_sched_barrier(0);

        #pragma unroll
        for (int kh = 0; kh < 2; ++kh) {
            s8v a[4], b[2];
            #pragma unroll
            for (int mf = 0; mf < 4; ++mf)
                a[mf] = *reinterpret_cast<const s8v*>(&LA[cur][kh][wr * 64 + mf * 16 + lrow][kg]);
            #pragma unroll
            for (int nf = 0; nf < 2; ++nf)
                b[nf] = *reinterpret_cast<const s8v*>(&LB[cur][kh][wc * 32 + nf * 16 + lrow][kg]);
            #pragma unroll
            for (int mf = 0; mf < 4; ++mf)
                #pragma unroll
                for (int nf = 0; nf < 2; ++nf)
                    acc[mf][nf] = __builtin_amdgcn_mfma_f32_16x16x32_bf16(a[mf], b[nf], acc[mf][nf], 0, 0, 0);
        }

        __builtin_amdgcn_sched_barrier(0);
        asm volatile("s_waitcnt lgkmcnt(0)" ::: "memory");
        __builtin_amdgcn_s_barrier();
    }
#undef STAGE2

    #pragma unroll
    for (int nf = 0; nf < 2; ++nf) {
        const int col = bn + wc * 32 + nf * 16 + lrow;
        if (col >= Cv) continue;
        #pragma unroll
        for (int mf = 0; mf < 4; ++mf) {
            #pragma unroll
            for (int r = 0; r < 4; ++r) {
                const int row = bm + wr * 64 + mf * 16 + (lane >> 4) * 4 + r;
                out[(size_t)row * Cv + col] = acc[mf][nf][r];
            }
        }
    }
}

// ---------------------------------------------------------------------------
extern "C" void kernel_launch(void* const* d_in, const int* in_sizes, int n_in,
                              void* d_out, int out_size, void* d_ws, size_t ws_size,
                              hipStream_t stream) {
    const float* x  = (const float*)d_in[0];  // [B, D]
    const float* sw = (const float*)d_in[1];  // [T, NI, D]
    const float* sb = (const float*)d_in[2];  // [T, NI]
    const float* ll = (const float*)d_in[3];  // [T, NL, C]
    const float* tw = (const float*)d_in[4];  // [T]
    const float* lt = (const float*)d_in[5];  // scalar

    float* out  = (float*)d_out;              // [B, C]
    float* ws   = (float*)d_ws;
    _Float16* Xh = (_Float16*)(ws + OFF_XH);
    _Float16* Wh = (_Float16*)(ws + OFF_WH);
    float* Pbuf = ws + OFF_P;
    unsigned short* MH  = (unsigned short*)(ws + OFF_MH);
    unsigned short* PTH = (unsigned short*)(ws + OFF_PTH);

    k_prep<<<(int)(N_X / 1024 + N_W / 1024), 256, 0, stream>>>(x, sw, Xh, Wh);
    k_gemm1mu<<<512, 256, 0, stream>>>(Xh, Wh, sb, tw, lt, MH);
    k_leafsm<<<TL, 256, 0, stream>>>(ll, lt, Pbuf);
    k_tp<<<dim3(TL / 64, Npad / 64), 256, 0, stream>>>(Pbuf, PTH);
    k_gemm2<<<512, 256, 0, stream>>>(MH, PTH, out);
}

// Round 7
// 85.835 us; speedup vs baseline: 7.7644x; 1.0407x over previous
//
#include <hip/hip_runtime.h>
#include <cstdint>
#include <cstddef>

// Problem dims
constexpr int Bv = 4096;   // batch
constexpr int Dv = 1024;   // feature dim
constexpr int Cv = 1000;   // classes
constexpr int Tv = 32;     // trees
constexpr int NI = 63;     // internal nodes per tree
constexpr int NL = 64;     // leaves per tree
constexpr int TNp = 2048;  // padded node dim: tree t at cols [64t, 64t+63]
constexpr int TL = Tv * NL;   // 2048
constexpr int Npad = 1024;    // padded class dim

typedef _Float16 h8  __attribute__((ext_vector_type(8)));
typedef _Float16 h4  __attribute__((ext_vector_type(4)));
typedef short    s8v __attribute__((ext_vector_type(8)));
typedef unsigned short us8 __attribute__((ext_vector_type(8)));
typedef float    f4v __attribute__((ext_vector_type(4)));

// ---------------------------------------------------------------------------
// Workspace layout (float units). Total ~40.5 MB.
// ---------------------------------------------------------------------------
constexpr size_t N_X    = (size_t)Bv * Dv;                 // 4M elems
constexpr size_t N_W    = (size_t)TNp * Dv;                // 2M elems (padded)
constexpr size_t OFF_XH = 64;                              // f16 [Bv][Dv]
constexpr size_t OFF_WH = OFF_XH + N_X / 2;                // f16 [TNp][Dv]
constexpr size_t OFF_P  = OFF_WH + N_W / 2;                // fp32 [TL][Cv]
constexpr size_t OFF_MH = OFF_P + (size_t)TL * Cv;         // bf16 [Bv][TL]
constexpr size_t OFF_PTH= OFF_MH + (size_t)Bv * TL / 2;    // bf16 [Npad][TL]

// bf16 round-to-nearest-even from fp32
__device__ __forceinline__ unsigned short f2bf_rn(float x) {
    unsigned u = __float_as_uint(x);
    return (unsigned short)((u + 0x7fffu + ((u >> 16) & 1u)) >> 16);
}

// async global->LDS, 16B per lane, LDS dest = wave-uniform base + lane*16
__device__ __forceinline__ void gll16(const void* gptr, void* lptr) {
    __builtin_amdgcn_global_load_lds(
        (const __attribute__((address_space(1))) unsigned int*)gptr,
        (__attribute__((address_space(3))) unsigned int*)lptr,
        16, 0, 0);
}

// ---------------------------------------------------------------------------
// Kernel A (grid-sectioned, all sections independent):
//   blocks [0, 4096)        : x fp32 -> Xh f16
//   blocks [4096, 6144)     : W re-pack rows (t*63+i)->(t*64+i), f16, pad 0
//   blocks [6144, 8192)     : leaf softmax row -> fp32 P
// ---------------------------------------------------------------------------
__global__ __launch_bounds__(256)
void k_prep_leaf(const float* __restrict__ x, const float* __restrict__ sw,
                 const float* __restrict__ ll, const float* __restrict__ lt,
                 _Float16* __restrict__ Xh, _Float16* __restrict__ Wh,
                 float* __restrict__ P) {
    const int b = blockIdx.x;
    const int tid = threadIdx.x;
    if (b < 4096) {
        const size_t i4 = ((size_t)b * 256 + tid) * 4;
        const float4 v = *reinterpret_cast<const float4*>(&x[i4]);
        h4 vh;
        vh[0] = (_Float16)v.x; vh[1] = (_Float16)v.y;
        vh[2] = (_Float16)v.z; vh[3] = (_Float16)v.w;
        *reinterpret_cast<h4*>(&Xh[i4]) = vh;
    } else if (b < 6144) {
        const size_t d4 = ((size_t)(b - 4096) * 256 + tid) * 4;
        const int row = (int)(d4 >> 10);
        const int col = (int)(d4 & 1023);
        const int t = row >> 6, i = row & 63;
        float4 v = make_float4(0.f, 0.f, 0.f, 0.f);
        if (i < NI)
            v = *reinterpret_cast<const float4*>(&sw[(size_t)(t * NI + i) * Dv + col]);
        h4 vh;
        vh[0] = (_Float16)v.x; vh[1] = (_Float16)v.y;
        vh[2] = (_Float16)v.z; vh[3] = (_Float16)v.w;
        *reinterpret_cast<h4*>(&Wh[d4]) = vh;
    } else {
        const int r = b - 6144;
        const float temp = fminf(fmaxf(expf(lt[0]), 0.1f), 5.0f);
        const float invT = 1.0f / temp;
        const float* row = ll + (size_t)r * Cv;
        float* pr = P + (size_t)r * Cv;
        __shared__ float redm[4];
        __shared__ float reds[4];

        float m = -3.4e38f;
        for (int c = tid; c < Cv; c += 256) m = fmaxf(m, row[c] * invT);
        #pragma unroll
        for (int o = 32; o > 0; o >>= 1) m = fmaxf(m, __shfl_down(m, o));
        if ((tid & 63) == 0) redm[tid >> 6] = m;
        __syncthreads();
        m = fmaxf(fmaxf(redm[0], redm[1]), fmaxf(redm[2], redm[3]));

        float sum = 0.f;
        for (int c = tid; c < Cv; c += 256) {
            const float e = expf(row[c] * invT - m);
            pr[c] = e;
            sum += e;
        }
        #pragma unroll
        for (int o = 32; o > 0; o >>= 1) sum += __shfl_down(sum, o);
        if ((tid & 63) == 0) reds[tid >> 6] = sum;
        __syncthreads();
        sum = reds[0] + reds[1] + reds[2] + reds[3];
        const float rs = 1.0f / sum;
        for (int c = tid; c < Cv; c += 256) pr[c] *= rs;
    }
}

// ---------------------------------------------------------------------------
// Kernel B (grid-sectioned):
//   blocks [0, 512)    : GEMM1+mu fused (128x128 tile, BK=64, dbuf,
//                        counted vmcnt(8); sigmoid->LDS transpose->path
//                        product -> MH bf16)
//   blocks [512, 1024) : transpose P fp32 [TL][Cv] -> PTH bf16 [Npad][TL]
// Both only feed gemm2; tp rides in gemm1mu's scheduling tail.
// ---------------------------------------------------------------------------
__global__ __launch_bounds__(256, 2)
void k_gemm1mu_tp(const _Float16* __restrict__ Xh, const _Float16* __restrict__ Wh,
                  const float* __restrict__ bias, const float* __restrict__ tw,
                  const float* __restrict__ lt, const float* __restrict__ P,
                  unsigned short* __restrict__ MH, unsigned short* __restrict__ PTH) {
    // union: staging 2buf x (A 16KB + B 16KB) = 64 KB; epilogue scratch
    // 4 waves x [64][65] f32 = 66,560 B; tp tile 16,640 B
    __shared__ __align__(16) char lds[4 * 64 * 65 * 4];

    const int tid = threadIdx.x;

    if (blockIdx.x >= 512) {
        // ---------------- transpose-P section ----------------
        const int tpb = blockIdx.x - 512;
        const int k0 = (tpb & 31) * 64;
        const int c0 = (tpb >> 5) * 64;
        float* T = (float*)lds;   // [64][65]
        #pragma unroll
        for (int i = 0; i < 16; ++i) {
            const int idx = tid + i * 256;
            const int kk = idx >> 6, cc = idx & 63;
            const int c = c0 + cc;
            T[kk * 65 + cc] = (c < Cv) ? P[(size_t)(k0 + kk) * Cv + c] : 0.f;
        }
        __syncthreads();
        #pragma unroll
        for (int i = 0; i < 16; ++i) {
            const int idx = tid + i * 256;
            const int cc = idx >> 6, kk = idx & 63;
            PTH[(size_t)(c0 + cc) * TL + k0 + kk] = f2bf_rn(T[kk * 65 + cc]);
        }
        return;
    }

    // ---------------- GEMM1+mu section ----------------
    // XCD swizzle: 512 wgs, 8 chunks of 64 = 16(by) x 4(bx) sub-blocks
    const int wg  = (blockIdx.x & 7) * 64 + (blockIdx.x >> 3);
    const int blk = wg >> 6;
    const int j   = wg & 63;
    const int bx  = (blk & 3) * 4 + (j & 3);       // 0..15
    const int by  = (blk >> 2) * 16 + (j >> 2);    // 0..31
    const int bm = by * 128, bn = bx * 128;

    const int lane = tid & 63, wv = tid >> 6;
    const int wr = wv >> 1, wc = wv & 1;
    const int lrow = lane & 15, kg = (lane >> 4) * 8;
    const int sr = lane >> 3;            // staging row within 8-row chunk
    const int sc = (lane & 7) * 8;       // staging f16 col (0..56)

    // scalars inline
    const float temp = fminf(fmaxf(expf(lt[0]), 0.1f), 5.0f);
    const float invT = 1.0f / temp;
    const int mytree = 2 * bx + wc;
    float wm = -3.4e38f;
    #pragma unroll
    for (int t = 0; t < Tv; ++t) wm = fmaxf(wm, tw[t]);
    float wsum = 0.f, wmine = 0.f;
    #pragma unroll
    for (int t = 0; t < Tv; ++t) {
        const float e = expf(tw[t] - wm);
        wsum += e;
        if (t == mytree) wmine = e;
    }
    const float wt = wmine / wsum;

    f4v acc[4][4] = {};

    // BK=64: slab 128x64 f16 = 16 KB = 16 chunks of 1KB (8 rows each);
    // 4 chunks/wave/slab -> 8 gll16 issues per wave per tile
#define STG(bufi, k0)                                                         \
    { _Pragma("unroll")                                                       \
      for (int i_ = 0; i_ < 4; ++i_) {                                        \
        const int ch_  = wv * 4 + i_;                                         \
        const int row_ = ch_ * 8 + sr;                                        \
        gll16(&Xh[(size_t)(bm + row_) * Dv + (k0) + sc],                      \
              lds + (bufi) * 32768 + ch_ * 1024);                             \
        gll16(&Wh[(size_t)(bn + row_) * Dv + (k0) + sc],                      \
              lds + (bufi) * 32768 + 16384 + ch_ * 1024);                     \
      } }

    STG(0, 0);
    for (int t = 0; t < 16; ++t) {
        const int cur = t & 1;
        if (t < 15) {
            STG(cur ^ 1, (t + 1) * 64);
            asm volatile("s_waitcnt vmcnt(8)" ::: "memory");  // current tile's 8 done
        } else {
            asm volatile("s_waitcnt vmcnt(0)" ::: "memory");
        }
        __builtin_amdgcn_s_barrier();
        __builtin_amdgcn_sched_barrier(0);

        #pragma unroll
        for (int kh = 0; kh < 2; ++kh) {
            h8 a[4], b[4];
            #pragma unroll
            for (int mf = 0; mf < 4; ++mf)
                a[mf] = *reinterpret_cast<const h8*>(
                    lds + cur * 32768 + ((wr * 64 + mf * 16 + lrow) * 64 + kh * 32 + kg) * 2);
            #pragma unroll
            for (int nf = 0; nf < 4; ++nf)
                b[nf] = *reinterpret_cast<const h8*>(
                    lds + cur * 32768 + 16384 + ((wc * 64 + nf * 16 + lrow) * 64 + kh * 32 + kg) * 2);
            #pragma unroll
            for (int mf = 0; mf < 4; ++mf)
                #pragma unroll
                for (int nf = 0; nf < 4; ++nf)
                    acc[mf][nf] = __builtin_amdgcn_mfma_f32_16x16x32_f16(a[mf], b[nf], acc[mf][nf], 0, 0, 0);
        }

        __builtin_amdgcn_sched_barrier(0);
        asm volatile("s_waitcnt lgkmcnt(0)" ::: "memory");
        __builtin_amdgcn_s_barrier();   // safe to overwrite cur next iter
    }
#undef STG

    // ---- epilogue: sigmoid -> per-wave [64 rows][65] f32 scratch ----
    float* scr = (float*)lds + wv * (64 * 65);
    #pragma unroll
    for (int nf = 0; nf < 4; ++nf) {
        const int colB = nf * 16 + lrow;                 // node idx 0..63
        const int gcol = bn + wc * 64 + colB;
        const int ii = gcol & 63;
        const float bv = (ii < NI) ? bias[(gcol >> 6) * NI + ii] : 0.f;
        #pragma unroll
        for (int mf = 0; mf < 4; ++mf) {
            #pragma unroll
            for (int r = 0; r < 4; ++r) {
                const int rowB = mf * 16 + (lane >> 4) * 4 + r;
                const float z = (acc[mf][nf][r] + bv) * invT;
                scr[rowB * 65 + colB] = 1.0f / (1.0f + __expf(-z));
            }
        }
    }
    asm volatile("s_waitcnt lgkmcnt(0)" ::: "memory");   // wave-local writes done

    // ---- per-lane mu: row = lane, tree = mytree ----
    const float* srow = scr + lane * 65;
    float mu[NL];
    mu[0] = wt;
    #pragma unroll
    for (int d = 0; d < 6; ++d) {
        const int width = 1 << d;
        #pragma unroll
        for (int i = width - 1; i >= 0; --i) {
            const float sv = srow[width - 1 + i];
            const float m  = mu[i];
            mu[2 * i + 1] = m * sv;
            mu[2 * i]     = m * (1.0f - sv);
        }
    }
    const size_t obase = (size_t)(bm + wr * 64 + lane) * TL + (size_t)mytree * 64;
    #pragma unroll
    for (int c = 0; c < 8; ++c) {
        us8 vh;
        #pragma unroll
        for (int jj = 0; jj < 8; ++jj) vh[jj] = f2bf_rn(mu[c * 8 + jj]);
        *reinterpret_cast<us8*>(&MH[obase + c * 8]) = vh;
    }
}

// ---------------------------------------------------------------------------
// GEMM2 (single-pass bf16): out = muw @ P. A = MH [Bv][TL], B = PTH [Npad][TL].
// 128x64 tile, K-step 64 (two 32-sub-steps), double-buffered, counted vmcnt.
// XCD swizzle: chunks of 64 = 8(bm) x 8(bn) sub-blocks.
// ---------------------------------------------------------------------------
__global__ __launch_bounds__(256, 2)
void k_gemm2(const unsigned short* __restrict__ MH, const unsigned short* __restrict__ PTH,
             float* __restrict__ out) {
    __shared__ unsigned short LA[2][2][128][32];   // 32 KB
    __shared__ unsigned short LB[2][2][64][32];    // 16 KB

    const int tid  = threadIdx.x;
    const int wg  = (blockIdx.x & 7) * 64 + (blockIdx.x >> 3);
    const int blk = wg >> 6;                        // 0..7
    const int j   = wg & 63;
    const int bnt = (blk & 1) * 8 + (j & 7);        // 0..15
    const int bmt = (blk >> 1) * 8 + (j >> 3);      // 0..31
    const int bm = bmt * 128, bn = bnt * 64;

    const int lane = tid & 63;
    const int wv   = tid >> 6;
    const int wr   = wv >> 1;
    const int wc   = wv & 1;
    const int lrow = lane & 15;
    const int kg   = (lane >> 4) * 8;
    const int sr   = lane >> 2;
    const int sc   = (lane & 3) * 8;

    f4v acc[4][2] = {};

#define STAGE2(bufi, k0)                                                          \
    { _Pragma("unroll")                                                           \
      for (int kh_ = 0; kh_ < 2; ++kh_) {                                         \
        _Pragma("unroll")                                                         \
        for (int i_ = 0; i_ < 2; ++i_) {                                          \
          const int ch_  = wv * 2 + i_;                                           \
          const int row_ = ch_ * 16 + sr;                                         \
          gll16(&MH[(size_t)(bm + row_) * TL + (k0) + kh_ * 32 + sc],             \
                (char*)&LA[bufi][kh_][0][0] + ch_ * 1024);                        \
        }                                                                         \
        { const int row_ = wv * 16 + sr;                                          \
          gll16(&PTH[(size_t)(bn + row_) * TL + (k0) + kh_ * 32 + sc],            \
                (char*)&LB[bufi][kh_][0][0] + wv * 1024); }                       \
      } }

    STAGE2(0, 0);
    for (int t = 0; t < 32; ++t) {
        const int cur = t & 1;
        if (t < 31) {
            STAGE2(cur ^ 1, (t + 1) * 64);
            asm volatile("s_waitcnt vmcnt(6)" ::: "memory");
        } else {
            asm volatile("s_waitcnt vmcnt(0)" ::: "memory");
        }
        __builtin_amdgcn_s_barrier();
        __builtin_amdgcn_sched_barrier(0);

        #pragma unroll
        for (int kh = 0; kh < 2; ++kh) {
            s8v a[4], b[2];
            #pragma unroll
            for (int mf = 0; mf < 4; ++mf)
                a[mf] = *reinterpret_cast<const s8v*>(&LA[cur][kh][wr * 64 + mf * 16 + lrow][kg]);
            #pragma unroll
            for (int nf = 0; nf < 2; ++nf)
                b[nf] = *reinterpret_cast<const s8v*>(&LB[cur][kh][wc * 32 + nf * 16 + lrow][kg]);
            #pragma unroll
            for (int mf = 0; mf < 4; ++mf)
                #pragma unroll
                for (int nf = 0; nf < 2; ++nf)
                    acc[mf][nf] = __builtin_amdgcn_mfma_f32_16x16x32_bf16(a[mf], b[nf], acc[mf][nf], 0, 0, 0);
        }

        __builtin_amdgcn_sched_barrier(0);
        asm volatile("s_waitcnt lgkmcnt(0)" ::: "memory");
        __builtin_amdgcn_s_barrier();
    }
#undef STAGE2

    #pragma unroll
    for (int nf = 0; nf < 2; ++nf) {
        const int col = bn + wc * 32 + nf * 16 + lrow;
        if (col >= Cv) continue;
        #pragma unroll
        for (int mf = 0; mf < 4; ++mf) {
            #pragma unroll
            for (int r = 0; r < 4; ++r) {
                const int row = bm + wr * 64 + mf * 16 + (lane >> 4) * 4 + r;
                out[(size_t)row * Cv + col] = acc[mf][nf][r];
            }
        }
    }
}

// ---------------------------------------------------------------------------
extern "C" void kernel_launch(void* const* d_in, const int* in_sizes, int n_in,
                              void* d_out, int out_size, void* d_ws, size_t ws_size,
                              hipStream_t stream) {
    const float* x  = (const float*)d_in[0];  // [B, D]
    const float* sw = (const float*)d_in[1];  // [T, NI, D]
    const float* sb = (const float*)d_in[2];  // [T, NI]
    const float* ll = (const float*)d_in[3];  // [T, NL, C]
    const float* tw = (const float*)d_in[4];  // [T]
    const float* lt = (const float*)d_in[5];  // scalar

    float* out  = (float*)d_out;              // [B, C]
    float* ws   = (float*)d_ws;
    _Float16* Xh = (_Float16*)(ws + OFF_XH);
    _Float16* Wh = (_Float16*)(ws + OFF_WH);
    float* Pbuf = ws + OFF_P;
    unsigned short* MH  = (unsigned short*)(ws + OFF_MH);
    unsigned short* PTH = (unsigned short*)(ws + OFF_PTH);

    k_prep_leaf<<<8192, 256, 0, stream>>>(x, sw, ll, lt, Xh, Wh, Pbuf);
    k_gemm1mu_tp<<<1024, 256, 0, stream>>>(Xh, Wh, sb, tw, lt, Pbuf, MH, PTH);
    k_gemm2<<<512, 256, 0, stream>>>(MH, PTH, out);
}